// Round 1
// baseline (1665.524 us; speedup 1.0000x reference)
//
#include <hip/hip_runtime.h>

// Problem constants (fixed by the reference)
#define N_TXN   100000
#define N_ADDRN 100000
#define NEDGE   1000000
#define NGRAPH  128

// Workspace layout (in floats). Regions [0, INIT_N) are initialized every call.
#define OFF_ACC   0                      // [N_TX, 64] feature accumulator
#define OFF_DEN   6400000                // [N_TX, 4]  softmax denominators
#define OFF_MKEY  6800000                // [N_TX, 4]  uint-mapped running max
#define OFF_G     7200000                // [128, 64]  pooled graph sums
#define OFF_CNT   7208192                // [128]      node counts per graph
#define INIT_N    7208320
#define OFF_Z     7208320                // [N_ADDR, 64] z_addr features
#define OFF_SS    13608320               // [N_ADDR, 4] (z_addr . att_src_at)
#define OFF_SD    14008320               // [N_TX, 4]   (z_tx . att_dst_at)

#define NEG_KEY 0x007FFFFFu              // fkey(-inf)

__device__ __forceinline__ unsigned fkey(float f) {
    unsigned b = __float_as_uint(f);
    return (b & 0x80000000u) ? ~b : (b | 0x80000000u);
}
__device__ __forceinline__ float fval(unsigned k) {
    unsigned b = (k & 0x80000000u) ? (k ^ 0x80000000u) : ~k;
    return __uint_as_float(b);
}

// Zero accumulators; set running-max keys to fkey(-inf).
__global__ void init_kernel(float* __restrict__ ws) {
    int i = blockIdx.x * blockDim.x + threadIdx.x;
    if (i >= INIT_N) return;
    if (i >= OFF_MKEY && i < OFF_MKEY + N_TXN * 4)
        ((unsigned*)ws)[i] = NEG_KEY;
    else
        ws[i] = 0.0f;
}

// Fused projection chain for one node type: h = x@Wp + bp ; z = h@Wh + bh.
// One wave (64 lanes) per node; lane d owns output feature d. Weights staged
// in LDS; x row broadcast via __shfl. Optionally stores z; always stores the
// per-head attention dot s[n,h] = sum_d z[n,h,d]*att[h*16+d].
__global__ __launch_bounds__(256) void proj_kernel(
    const float* __restrict__ x, int n_nodes,
    const float* __restrict__ Wp, const float* __restrict__ bp,
    const float* __restrict__ Wh, const float* __restrict__ bh,
    const float* __restrict__ att,      // 64 floats, flattened [H,D]
    float* __restrict__ z_out,          // may be nullptr
    float* __restrict__ s_out)          // [n_nodes, 4]
{
    __shared__ float Wp_s[65 * 64];
    __shared__ float Wh_s[64 * 64];
    for (int i = threadIdx.x; i < 65 * 64; i += 256) Wp_s[i] = Wp[i];
    for (int i = threadIdx.x; i < 64 * 64; i += 256) Wh_s[i] = Wh[i];
    __syncthreads();

    int lane = threadIdx.x & 63;
    int node = (blockIdx.x * blockDim.x + threadIdx.x) >> 6;
    if (node >= n_nodes) return;

    float xv = x[node * 65 + lane];      // x[0..63]
    float xl = x[node * 65 + 64];        // x[64] (broadcast read)

    float h = bp[lane];
    #pragma unroll
    for (int k = 0; k < 64; ++k) h += __shfl(xv, k) * Wp_s[k * 64 + lane];
    h += xl * Wp_s[64 * 64 + lane];

    float z = bh[lane];
    #pragma unroll
    for (int k = 0; k < 64; ++k) z += __shfl(h, k) * Wh_s[k * 64 + lane];

    if (z_out) z_out[node * 64 + lane] = z;

    // per-head (16-lane group) reduction of z*att
    float p = z * att[lane];
    p += __shfl_xor(p, 1);
    p += __shfl_xor(p, 2);
    p += __shfl_xor(p, 4);
    p += __shfl_xor(p, 8);
    if ((lane & 15) == 0) s_out[node * 4 + (lane >> 4)] = p;
}

// Edge pass 1: alpha = leaky_relu(s_src[src] + s_dst[dst]); segment max by dst.
__global__ __launch_bounds__(256) void edge_max_kernel(
    const int* __restrict__ e_src, const int* __restrict__ e_dst,
    const float* __restrict__ s_src, const float* __restrict__ s_dst,
    unsigned* __restrict__ mkey)
{
    int e = blockIdx.x * blockDim.x + threadIdx.x;
    if (e >= NEDGE) return;
    int s = e_src[e], d = e_dst[e];
    float4 as = *(const float4*)(s_src + s * 4);
    float4 ad = *(const float4*)(s_dst + d * 4);
    float a;
    a = as.x + ad.x; a = a >= 0.f ? a : 0.2f * a; atomicMax(&mkey[d * 4 + 0], fkey(a));
    a = as.y + ad.y; a = a >= 0.f ? a : 0.2f * a; atomicMax(&mkey[d * 4 + 1], fkey(a));
    a = as.z + ad.z; a = a >= 0.f ? a : 0.2f * a; atomicMax(&mkey[d * 4 + 2], fkey(a));
    a = as.w + ad.w; a = a >= 0.f ? a : 0.2f * a; atomicMax(&mkey[d * 4 + 3], fkey(a));
}

// Edge pass 2: w = exp(alpha - m[dst]); denom[dst] += w; acc[dst] += z[src]*w.
// 16 lanes per edge; lane sub owns features [4*sub, 4*sub+4), head = sub>>2.
__global__ __launch_bounds__(256) void edge_scatter_kernel(
    const int* __restrict__ e_src, const int* __restrict__ e_dst,
    const float* __restrict__ s_src, const float* __restrict__ s_dst,
    const unsigned* __restrict__ mkey,
    const float* __restrict__ z,
    float* __restrict__ acc, float* __restrict__ denom)
{
    int tid = blockIdx.x * blockDim.x + threadIdx.x;
    int e = tid >> 4;
    if (e >= NEDGE) return;
    int sub = tid & 15;
    int h = sub >> 2;
    int s = e_src[e], d = e_dst[e];
    float a = s_src[s * 4 + h] + s_dst[d * 4 + h];
    a = a >= 0.f ? a : 0.2f * a;
    float m = fval(mkey[d * 4 + h]);
    float w = __expf(a - m);
    if ((sub & 3) == 0) atomicAdd(&denom[d * 4 + h], w);
    float4 zz = *(const float4*)(z + s * 64 + sub * 4);
    float* ap = acc + d * 64 + sub * 4;
    atomicAdd(ap + 0, zz.x * w);
    atomicAdd(ap + 1, zz.y * w);
    atomicAdd(ap + 2, zz.z * w);
    atomicAdd(ap + 3, zz.w * w);
}

// Finalize: tx_feat = relu(acc/denom); mean-pool by (sorted) batch id.
// Thread owns feature d over a chunk of 16 consecutive nodes; runs of equal
// batch id are accumulated locally before one atomic per run.
#define POOL_CH 16
__global__ __launch_bounds__(256) void finalize_pool_kernel(
    const float* __restrict__ acc, const float* __restrict__ denom,
    const int* __restrict__ batch,
    float* __restrict__ g, float* __restrict__ cnt)
{
    int tid = blockIdx.x * blockDim.x + threadIdx.x;
    int chunk = tid >> 6;
    int d = tid & 63;
    int n0 = chunk * POOL_CH;
    if (n0 >= N_TXN) return;
    int n1 = n0 + POOL_CH; if (n1 > N_TXN) n1 = N_TXN;

    float run = 0.f, runc = 0.f;
    int cb = batch[n0];
    for (int node = n0; node < n1; ++node) {
        int b = batch[node];
        if (b != cb) {
            atomicAdd(&g[cb * 64 + d], run);
            if (d == 0) atomicAdd(&cnt[cb], runc);
            run = 0.f; runc = 0.f; cb = b;
        }
        float v = acc[node * 64 + d] / (denom[node * 4 + (d >> 4)] + 1e-16f);
        run += fmaxf(v, 0.f);
        runc += 1.f;
    }
    atomicAdd(&g[cb * 64 + d], run);
    if (d == 0) atomicAdd(&cnt[cb], runc);
}

// Classifier: out = relu(gmean @ W1 + b1) @ W2 + b2. One block, 128 threads.
__global__ __launch_bounds__(128) void classifier_kernel(
    const float* __restrict__ g, const float* __restrict__ cnt,
    const float* __restrict__ W1, const float* __restrict__ b1,
    const float* __restrict__ W2, const float* __restrict__ b2,
    float* __restrict__ out)
{
    __shared__ float W1s[64 * 32];
    __shared__ float W2s[32];
    int t = threadIdx.x;
    for (int i = t; i < 64 * 32; i += 128) W1s[i] = W1[i];
    if (t < 32) W2s[t] = W2[t];
    __syncthreads();
    if (t >= NGRAPH) return;

    float c = fmaxf(cnt[t], 1.0f);
    float gm[64];
    #pragma unroll
    for (int k = 0; k < 64; ++k) gm[k] = g[t * 64 + k] / c;

    float o = b2[0];
    for (int j = 0; j < 32; ++j) {
        float acc = b1[j];
        #pragma unroll
        for (int k = 0; k < 64; ++k) acc += gm[k] * W1s[k * 32 + j];
        o += fmaxf(acc, 0.f) * W2s[j];
    }
    out[t] = o;
}

extern "C" void kernel_launch(void* const* d_in, const int* in_sizes, int n_in,
                              void* d_out, int out_size, void* d_ws, size_t ws_size,
                              hipStream_t stream)
{
    (void)in_sizes; (void)n_in; (void)out_size; (void)ws_size;

    const float* x_tx      = (const float*)d_in[0];
    const float* x_addr    = (const float*)d_in[1];
    const float* Wp_tx     = (const float*)d_in[2];
    const float* bp_tx     = (const float*)d_in[3];
    const float* Wp_ad     = (const float*)d_in[4];
    const float* bp_ad     = (const float*)d_in[5];
    const float* Wh_tx     = (const float*)d_in[6];
    const float* bh_tx     = (const float*)d_in[7];
    const float* Wh_ad     = (const float*)d_in[8];
    const float* bh_ad     = (const float*)d_in[9];
    // d_in[10],[11]: att_*_ta — dead (out_addr is discarded by the reference)
    const float* att_src_at = (const float*)d_in[12];
    const float* att_dst_at = (const float*)d_in[13];
    // d_in[14..16]: W_k,b_k,q — dead (softmax over 1 metapath == identity)
    const float* W_c1      = (const float*)d_in[17];
    const float* b_c1      = (const float*)d_in[18];
    const float* W_c2      = (const float*)d_in[19];
    const float* b_c2      = (const float*)d_in[20];
    // d_in[21]: edge_ta — dead
    const int*   edge_at   = (const int*)d_in[22];   // [2, E] row-major
    const int*   batch_tx  = (const int*)d_in[23];

    float* ws   = (float*)d_ws;
    float* acc  = ws + OFF_ACC;
    float* den  = ws + OFF_DEN;
    unsigned* mkey = (unsigned*)(ws + OFF_MKEY);
    float* g    = ws + OFF_G;
    float* cnt  = ws + OFF_CNT;
    float* z_ad = ws + OFF_Z;
    float* s_src = ws + OFF_SS;
    float* s_dst = ws + OFF_SD;

    const int* e_src = edge_at;          // addr ids (source)
    const int* e_dst = edge_at + NEDGE;  // tx ids (destination)

    init_kernel<<<(INIT_N + 255) / 256, 256, 0, stream>>>(ws);

    // z_addr (features kept) + s_src = (z_addr . att_src_at)
    proj_kernel<<<(N_ADDRN * 64) / 256, 256, 0, stream>>>(
        x_addr, N_ADDRN, Wp_ad, bp_ad, Wh_ad, bh_ad, att_src_at, z_ad, s_src);
    // z_tx dots only: s_dst = (z_tx . att_dst_at)
    proj_kernel<<<(N_TXN * 64) / 256, 256, 0, stream>>>(
        x_tx, N_TXN, Wp_tx, bp_tx, Wh_tx, bh_tx, att_dst_at, nullptr, s_dst);

    edge_max_kernel<<<(NEDGE + 255) / 256, 256, 0, stream>>>(
        e_src, e_dst, s_src, s_dst, mkey);

    edge_scatter_kernel<<<(NEDGE * 16) / 256, 256, 0, stream>>>(
        e_src, e_dst, s_src, s_dst, mkey, z_ad, acc, den);

    int nchunk = (N_TXN + POOL_CH - 1) / POOL_CH;
    finalize_pool_kernel<<<(nchunk * 64 + 255) / 256, 256, 0, stream>>>(
        acc, den, batch_tx, g, cnt);

    classifier_kernel<<<1, 128, 0, stream>>>(
        g, cnt, W_c1, b_c1, W_c2, b_c2, (float*)d_out);
}

// Round 2
// 799.583 us; speedup vs baseline: 2.0830x; 2.0830x over previous
//
#include <hip/hip_runtime.h>

// Problem constants (fixed by the reference)
#define N_TXN   100000
#define N_ADDRN 100000
#define NEDGE   1000000
#define NGRAPH  128
#define NBLK_SCAN ((N_TXN + 255) / 256)    // 391

// Workspace layout in 4-byte units
#define OFF_Z     0            // [N_ADDR*64] f32  z_addr features
#define OFF_TXF   6400000      // [N_TX*64]  f32  tx_feat (post relu/softmax)
#define OFF_SS    12800000     // [N_ADDR*4] f32  (z_addr . att_src_at)
#define OFF_SD    13200000     // [N_TX*4]   f32  (z_tx . att_dst_at)
#define OFF_CSR   13600000     // [E]        int  src ids grouped by dst
#define OFF_OFFS  14600000     // [N_TX]     int  deg -> exclusive offsets
#define OFF_CUR   14700000     // [N_TX]     int  fill cursor (ends = row end)
#define OFF_BSUM  14800000     // [512]      int  scan block sums
#define OFF_BPRE  14800512     // [512]      int  scan block prefixes
#define OFF_G     14801024     // [128*64]   f32  pooled graph sums
#define OFF_CNT   14809216     // [128]      f32  node counts per graph

// Zero the regions that must start at 0: deg, g, cnt.
__global__ void init_kernel(float* __restrict__ ws) {
    int i = blockIdx.x * blockDim.x + threadIdx.x;
    if (i < N_TXN) ((int*)ws)[OFF_OFFS + i] = 0;
    if (i < NGRAPH * 64) ws[OFF_G + i] = 0.0f;
    if (i < NGRAPH) ws[OFF_CNT + i] = 0.0f;
}

// Fused projection chain for one node type: h = x@Wp + bp ; z = h@Wh + bh.
// One wave per node; lane d owns output feature d. Weights staged in LDS.
// Optionally stores z; always stores per-head dot s[n,h] = sum_d z*att.
__global__ __launch_bounds__(256) void proj_kernel(
    const float* __restrict__ x, int n_nodes,
    const float* __restrict__ Wp, const float* __restrict__ bp,
    const float* __restrict__ Wh, const float* __restrict__ bh,
    const float* __restrict__ att,      // 64 floats, flattened [H,D]
    float* __restrict__ z_out,          // may be nullptr
    float* __restrict__ s_out)          // [n_nodes, 4]
{
    __shared__ float Wp_s[65 * 64];
    __shared__ float Wh_s[64 * 64];
    for (int i = threadIdx.x; i < 65 * 64; i += 256) Wp_s[i] = Wp[i];
    for (int i = threadIdx.x; i < 64 * 64; i += 256) Wh_s[i] = Wh[i];
    __syncthreads();

    int lane = threadIdx.x & 63;
    int node = (blockIdx.x * blockDim.x + threadIdx.x) >> 6;
    if (node >= n_nodes) return;

    float xv = x[node * 65 + lane];
    float xl = x[node * 65 + 64];

    float h = bp[lane];
    #pragma unroll
    for (int k = 0; k < 64; ++k) h += __shfl(xv, k) * Wp_s[k * 64 + lane];
    h += xl * Wp_s[64 * 64 + lane];

    float z = bh[lane];
    #pragma unroll
    for (int k = 0; k < 64; ++k) z += __shfl(h, k) * Wh_s[k * 64 + lane];

    if (z_out) z_out[node * 64 + lane] = z;

    float p = z * att[lane];
    p += __shfl_xor(p, 1);
    p += __shfl_xor(p, 2);
    p += __shfl_xor(p, 4);
    p += __shfl_xor(p, 8);
    if ((lane & 15) == 0) s_out[node * 4 + (lane >> 4)] = p;
}

// CSR build 1: per-dst degree histogram.
__global__ __launch_bounds__(256) void hist_kernel(
    const int* __restrict__ e_dst, int* __restrict__ deg)
{
    int e = blockIdx.x * blockDim.x + threadIdx.x;
    if (e < NEDGE) atomicAdd(&deg[e_dst[e]], 1);
}

// CSR build 2a: in-place per-block exclusive scan; block totals to bsum.
__global__ __launch_bounds__(256) void scan_block_kernel(
    int* __restrict__ data, int* __restrict__ bsum, int n)
{
    __shared__ int s[256];
    int t = threadIdx.x;
    int i = blockIdx.x * 256 + t;
    int v = (i < n) ? data[i] : 0;
    s[t] = v;
    __syncthreads();
    for (int o = 1; o < 256; o <<= 1) {
        int add = (t >= o) ? s[t - o] : 0;
        __syncthreads();
        s[t] += add;
        __syncthreads();
    }
    if (i < n) data[i] = s[t] - v;           // exclusive
    if (t == 255) bsum[blockIdx.x] = s[255]; // inclusive total
}

// CSR build 2b: exclusive scan of block sums (single block, 512 threads).
__global__ __launch_bounds__(512) void scan_top_kernel(
    const int* __restrict__ bsum, int* __restrict__ bpre, int n)
{
    __shared__ int s[512];
    int t = threadIdx.x;
    int v = (t < n) ? bsum[t] : 0;
    s[t] = v;
    __syncthreads();
    for (int o = 1; o < 512; o <<= 1) {
        int add = (t >= o) ? s[t - o] : 0;
        __syncthreads();
        s[t] += add;
        __syncthreads();
    }
    if (t < n) bpre[t] = s[t] - v;
}

// CSR build 2c: add block prefix; copy to fill cursor.
__global__ __launch_bounds__(256) void scan_add_kernel(
    int* __restrict__ offs, int* __restrict__ cur,
    const int* __restrict__ bpre, int n)
{
    int i = blockIdx.x * 256 + threadIdx.x;
    if (i < n) {
        int o = offs[i] + bpre[blockIdx.x];
        offs[i] = o;
        cur[i] = o;
    }
}

// CSR build 3: place src ids into dst-grouped slots.
__global__ __launch_bounds__(256) void fill_kernel(
    const int* __restrict__ e_src, const int* __restrict__ e_dst,
    int* __restrict__ cur, int* __restrict__ csr)
{
    int e = blockIdx.x * blockDim.x + threadIdx.x;
    if (e < NEDGE) {
        int p = atomicAdd(&cur[e_dst[e]], 1);
        csr[p] = e_src[e];
    }
}

// Fused edge phase: per-dst softmax (max, exp, sum) + weighted feature
// gather + normalize + relu. One wave per dst node; after fill_kernel,
// cur[dst] == row end. No atomics.
__global__ __launch_bounds__(256) void gather_kernel(
    const int* __restrict__ csr, const int* __restrict__ offs,
    const int* __restrict__ cur,
    const float* __restrict__ s_src, const float* __restrict__ s_dst,
    const float* __restrict__ z,
    float* __restrict__ txf)
{
    int dst = (blockIdx.x * blockDim.x + threadIdx.x) >> 6;
    if (dst >= N_TXN) return;
    int lane = threadIdx.x & 63;
    int r0 = offs[dst];
    int deg = cur[dst] - r0;

    float4 sd = *(const float4*)(s_dst + dst * 4);

    // pass 1: per-head segment max (leaky-relu'd scores)
    float4 mx = make_float4(-1e30f, -1e30f, -1e30f, -1e30f);
    for (int base = 0; base < deg; base += 64) {
        int e = base + lane;
        if (e < deg) {
            int s = csr[r0 + e];
            float4 ss = *(const float4*)(s_src + s * 4);
            float a;
            a = ss.x + sd.x; a = a >= 0.f ? a : 0.2f * a; mx.x = fmaxf(mx.x, a);
            a = ss.y + sd.y; a = a >= 0.f ? a : 0.2f * a; mx.y = fmaxf(mx.y, a);
            a = ss.z + sd.z; a = a >= 0.f ? a : 0.2f * a; mx.z = fmaxf(mx.z, a);
            a = ss.w + sd.w; a = a >= 0.f ? a : 0.2f * a; mx.w = fmaxf(mx.w, a);
        }
    }
    #pragma unroll
    for (int o = 1; o < 64; o <<= 1) {
        mx.x = fmaxf(mx.x, __shfl_xor(mx.x, o));
        mx.y = fmaxf(mx.y, __shfl_xor(mx.y, o));
        mx.z = fmaxf(mx.z, __shfl_xor(mx.z, o));
        mx.w = fmaxf(mx.w, __shfl_xor(mx.w, o));
    }

    // pass 2: exp weights, denominator, weighted feature accumulation
    int h = lane >> 4;
    float out = 0.f;
    float4 den = make_float4(0.f, 0.f, 0.f, 0.f);
    for (int base = 0; base < deg; base += 64) {
        int e = base + lane;
        int s = 0;
        float4 w = make_float4(0.f, 0.f, 0.f, 0.f);
        if (e < deg) {
            s = csr[r0 + e];
            float4 ss = *(const float4*)(s_src + s * 4);
            float a;
            a = ss.x + sd.x; a = a >= 0.f ? a : 0.2f * a; w.x = __expf(a - mx.x);
            a = ss.y + sd.y; a = a >= 0.f ? a : 0.2f * a; w.y = __expf(a - mx.y);
            a = ss.z + sd.z; a = a >= 0.f ? a : 0.2f * a; w.z = __expf(a - mx.z);
            a = ss.w + sd.w; a = a >= 0.f ? a : 0.2f * a; w.w = __expf(a - mx.w);
            den.x += w.x; den.y += w.y; den.z += w.z; den.w += w.w;
        }
        int cnt = deg - base; if (cnt > 64) cnt = 64;
        for (int ee = 0; ee < cnt; ++ee) {
            int se = __shfl(s, ee);
            float wx = __shfl(w.x, ee), wy = __shfl(w.y, ee);
            float wz = __shfl(w.z, ee), ww = __shfl(w.w, ee);
            float wl = (h == 0) ? wx : (h == 1) ? wy : (h == 2) ? wz : ww;
            out += z[se * 64 + lane] * wl;
        }
    }
    #pragma unroll
    for (int o = 1; o < 64; o <<= 1) {
        den.x += __shfl_xor(den.x, o);
        den.y += __shfl_xor(den.y, o);
        den.z += __shfl_xor(den.z, o);
        den.w += __shfl_xor(den.w, o);
    }
    float denh = (h == 0) ? den.x : (h == 1) ? den.y : (h == 2) ? den.z : den.w;
    txf[dst * 64 + lane] = fmaxf(out / (denh + 1e-16f), 0.f);
}

// Mean-pool by (sorted) batch id; run-accumulate before one atomic per run.
#define POOL_CH 16
__global__ __launch_bounds__(256) void pool_kernel(
    const float* __restrict__ txf, const int* __restrict__ batch,
    float* __restrict__ g, float* __restrict__ cnt)
{
    int tid = blockIdx.x * blockDim.x + threadIdx.x;
    int chunk = tid >> 6;
    int d = tid & 63;
    int n0 = chunk * POOL_CH;
    if (n0 >= N_TXN) return;
    int n1 = n0 + POOL_CH; if (n1 > N_TXN) n1 = N_TXN;

    float run = 0.f, runc = 0.f;
    int cb = batch[n0];
    for (int node = n0; node < n1; ++node) {
        int b = batch[node];
        if (b != cb) {
            atomicAdd(&g[cb * 64 + d], run);
            if (d == 0) atomicAdd(&cnt[cb], runc);
            run = 0.f; runc = 0.f; cb = b;
        }
        run += txf[node * 64 + d];
        runc += 1.f;
    }
    atomicAdd(&g[cb * 64 + d], run);
    if (d == 0) atomicAdd(&cnt[cb], runc);
}

// Classifier: out = relu(gmean @ W1 + b1) @ W2 + b2. One block, 128 threads.
__global__ __launch_bounds__(128) void classifier_kernel(
    const float* __restrict__ g, const float* __restrict__ cnt,
    const float* __restrict__ W1, const float* __restrict__ b1,
    const float* __restrict__ W2, const float* __restrict__ b2,
    float* __restrict__ out)
{
    __shared__ float W1s[64 * 32];
    __shared__ float W2s[32];
    int t = threadIdx.x;
    for (int i = t; i < 64 * 32; i += 128) W1s[i] = W1[i];
    if (t < 32) W2s[t] = W2[t];
    __syncthreads();
    if (t >= NGRAPH) return;

    float c = fmaxf(cnt[t], 1.0f);
    float gm[64];
    #pragma unroll
    for (int k = 0; k < 64; ++k) gm[k] = g[t * 64 + k] / c;

    float o = b2[0];
    for (int j = 0; j < 32; ++j) {
        float acc = b1[j];
        #pragma unroll
        for (int k = 0; k < 64; ++k) acc += gm[k] * W1s[k * 32 + j];
        o += fmaxf(acc, 0.f) * W2s[j];
    }
    out[t] = o;
}

extern "C" void kernel_launch(void* const* d_in, const int* in_sizes, int n_in,
                              void* d_out, int out_size, void* d_ws, size_t ws_size,
                              hipStream_t stream)
{
    (void)in_sizes; (void)n_in; (void)out_size; (void)ws_size;

    const float* x_tx      = (const float*)d_in[0];
    const float* x_addr    = (const float*)d_in[1];
    const float* Wp_tx     = (const float*)d_in[2];
    const float* bp_tx     = (const float*)d_in[3];
    const float* Wp_ad     = (const float*)d_in[4];
    const float* bp_ad     = (const float*)d_in[5];
    const float* Wh_tx     = (const float*)d_in[6];
    const float* bh_tx     = (const float*)d_in[7];
    const float* Wh_ad     = (const float*)d_in[8];
    const float* bh_ad     = (const float*)d_in[9];
    // d_in[10],[11]: att_*_ta — dead (out_addr discarded by the reference)
    const float* att_src_at = (const float*)d_in[12];
    const float* att_dst_at = (const float*)d_in[13];
    // d_in[14..16]: W_k,b_k,q — dead (softmax over 1 metapath == identity)
    const float* W_c1      = (const float*)d_in[17];
    const float* b_c1      = (const float*)d_in[18];
    const float* W_c2      = (const float*)d_in[19];
    const float* b_c2      = (const float*)d_in[20];
    // d_in[21]: edge_ta — dead
    const int*   edge_at   = (const int*)d_in[22];   // [2, E] row-major
    const int*   batch_tx  = (const int*)d_in[23];

    float* ws    = (float*)d_ws;
    float* z_ad  = ws + OFF_Z;
    float* txf   = ws + OFF_TXF;
    float* s_src = ws + OFF_SS;
    float* s_dst = ws + OFF_SD;
    int*   csr   = (int*)ws + OFF_CSR;
    int*   offs  = (int*)ws + OFF_OFFS;
    int*   cur   = (int*)ws + OFF_CUR;
    int*   bsum  = (int*)ws + OFF_BSUM;
    int*   bpre  = (int*)ws + OFF_BPRE;
    float* g     = ws + OFF_G;
    float* cnt   = ws + OFF_CNT;

    const int* e_src = edge_at;          // addr ids (source)
    const int* e_dst = edge_at + NEDGE;  // tx ids (destination)

    init_kernel<<<(N_TXN + 255) / 256, 256, 0, stream>>>(ws);

    proj_kernel<<<(N_ADDRN * 64) / 256, 256, 0, stream>>>(
        x_addr, N_ADDRN, Wp_ad, bp_ad, Wh_ad, bh_ad, att_src_at, z_ad, s_src);
    proj_kernel<<<(N_TXN * 64) / 256, 256, 0, stream>>>(
        x_tx, N_TXN, Wp_tx, bp_tx, Wh_tx, bh_tx, att_dst_at, nullptr, s_dst);

    hist_kernel<<<(NEDGE + 255) / 256, 256, 0, stream>>>(e_dst, offs);
    scan_block_kernel<<<NBLK_SCAN, 256, 0, stream>>>(offs, bsum, N_TXN);
    scan_top_kernel<<<1, 512, 0, stream>>>(bsum, bpre, NBLK_SCAN);
    scan_add_kernel<<<NBLK_SCAN, 256, 0, stream>>>(offs, cur, bpre, N_TXN);
    fill_kernel<<<(NEDGE + 255) / 256, 256, 0, stream>>>(e_src, e_dst, cur, csr);

    gather_kernel<<<(N_TXN * 64) / 256, 256, 0, stream>>>(
        csr, offs, cur, s_src, s_dst, z_ad, txf);

    int nchunk = (N_TXN + POOL_CH - 1) / POOL_CH;
    pool_kernel<<<(nchunk * 64 + 255) / 256, 256, 0, stream>>>(
        txf, batch_tx, g, cnt);

    classifier_kernel<<<1, 128, 0, stream>>>(
        g, cnt, W_c1, b_c1, W_c2, b_c2, (float*)d_out);
}

// Round 5
// 429.531 us; speedup vs baseline: 3.8775x; 1.8615x over previous
//
#include <hip/hip_runtime.h>

// Problem constants (fixed by the reference)
#define N_TXN   100000
#define N_ADDRN 100000
#define NEDGE   1000000
#define NGRAPH  128
#define NBLK_SCAN ((N_TXN + 255) / 256)    // 391

// Workspace layout in 4-byte units
#define OFF_Z     0            // [N_ADDR*64] f32  z_addr features
#define OFF_TXF   6400000      // [N_TX*64]  f32  tx_feat (post relu/softmax)
#define OFF_SS    12800000     // [N_ADDR*4] f32  (z_addr . att_src_at)
#define OFF_SD    13200000     // [N_TX*4]   f32  (z_tx . att_dst_at)
#define OFF_CSR   13600000     // [E]        int  src ids grouped by dst
#define OFF_OFFS  14600000     // [N_TX]     int  deg -> exclusive offsets
#define OFF_CUR   14700000     // [N_TX]     int  fill cursor (ends = row end)
#define OFF_BSUM  14800000     // [512]      int  scan block sums
#define OFF_BPRE  14800512     // [512]      int  scan block prefixes
#define OFF_G     14801024     // [128*64]   f32  pooled graph sums
#define OFF_CNT   14809216     // [128]      f32  counts per graph

// Zero the regions that must start at 0: deg(offs), g, cnt.
__global__ void init_kernel(float* __restrict__ ws) {
    int i = blockIdx.x * blockDim.x + threadIdx.x;
    if (i < N_TXN) ((int*)ws)[OFF_OFFS + i] = 0;
    if (i < NGRAPH * 64) ws[OFF_G + i] = 0.0f;
    if (i < NGRAPH) ws[OFF_CNT + i] = 0.0f;
}

// Two-stage projection, NUMERICS MATCH REFERENCE STAGING:
//   h = x@Wp + bp  (rounded to f32)   then   z = h@Wh + bh
// (round-3 lesson: folding Wp@Wh reassociates past the bf16-level output
//  tolerance; summation-order changes are fine, stage-elimination is not.)
// Tile: 64 nodes/block, 256 threads, each thread 4 nodes x 4 feats.
// k ascending, bias-first accumulation = round-2 order (absmax was 0.0).
#define PB 64
__global__ __launch_bounds__(256) void proj2_kernel(
    const float* __restrict__ x, int n_nodes,
    const float* __restrict__ Wp, const float* __restrict__ bp,
    const float* __restrict__ Wh, const float* __restrict__ bh,
    const float* __restrict__ att,      // 64 floats, flattened [H,D]
    float* __restrict__ z_out,          // may be nullptr (tx path)
    float* __restrict__ s_out)          // [n_nodes, 4]
{
    __shared__ float Wp_s[65 * 64];
    __shared__ float Wh_s[64 * 64];
    __shared__ float xh_s[PB * 68];     // x (65 used) then h (64 used); 68: f4 align + bank spread
    __shared__ float bp_s[64], bh_s[64], att_s[64];
    int t = threadIdx.x;
    int nb = blockIdx.x * PB;
    int nrem = n_nodes - nb; if (nrem > PB) nrem = PB;

    for (int i = t; i < 65 * 64; i += 256) Wp_s[i] = Wp[i];
    for (int i = t; i < 64 * 64; i += 256) Wh_s[i] = Wh[i];
    if (t < 64) { bp_s[t] = bp[t]; bh_s[t] = bh[t]; att_s[t] = att[t]; }
    int tot = nrem * 65;
    for (int i = t; i < tot; i += 256) {
        int n = i / 65, k = i - n * 65;
        xh_s[n * 68 + k] = x[nb * 65 + i];
    }
    __syncthreads();

    int ng = t >> 4;   // 16 node-groups x 4 nodes
    int fg = t & 15;   // float4 feature group
    const float4* Wpf = (const float4*)Wp_s;
    const float4* Whf = (const float4*)Wh_s;

    // stage 1: h = x@Wp + bp
    float4 acc[4];
    float4 b4 = ((const float4*)bp_s)[fg];
    #pragma unroll
    for (int i = 0; i < 4; ++i) acc[i] = b4;
    for (int k = 0; k < 65; ++k) {
        float4 w = Wpf[k * 16 + fg];
        #pragma unroll
        for (int i = 0; i < 4; ++i) {
            float xv = xh_s[(ng * 4 + i) * 68 + k];
            acc[i].x += xv * w.x; acc[i].y += xv * w.y;
            acc[i].z += xv * w.z; acc[i].w += xv * w.w;
        }
    }
    __syncthreads();    // all x reads done before overwrite
    #pragma unroll
    for (int i = 0; i < 4; ++i)
        *(float4*)(&xh_s[(ng * 4 + i) * 68 + fg * 4]) = acc[i];
    __syncthreads();    // h visible to all

    // stage 2: z = h@Wh + bh
    b4 = ((const float4*)bh_s)[fg];
    #pragma unroll
    for (int i = 0; i < 4; ++i) acc[i] = b4;
    for (int k = 0; k < 64; ++k) {
        float4 w = Whf[k * 16 + fg];
        #pragma unroll
        for (int i = 0; i < 4; ++i) {
            float hv = xh_s[(ng * 4 + i) * 68 + k];
            acc[i].x += hv * w.x; acc[i].y += hv * w.y;
            acc[i].z += hv * w.z; acc[i].w += hv * w.w;
        }
    }

    // epilogue: optional z store + per-head att dot
    float a0 = att_s[fg * 4], a1 = att_s[fg * 4 + 1];
    float a2 = att_s[fg * 4 + 2], a3 = att_s[fg * 4 + 3];
    #pragma unroll
    for (int i = 0; i < 4; ++i) {
        int n = ng * 4 + i;
        if (z_out && n < nrem)
            ((float4*)(z_out + (size_t)(nb + n) * 64))[fg] = acc[i];
        float p = acc[i].x * a0 + acc[i].y * a1 + acc[i].z * a2 + acc[i].w * a3;
        p += __shfl_xor(p, 1);
        p += __shfl_xor(p, 2);
        if ((fg & 3) == 0 && n < nrem)
            s_out[(nb + n) * 4 + (fg >> 2)] = p;
    }
}

// CSR build 1: per-dst degree histogram.
__global__ __launch_bounds__(256) void hist_kernel(
    const int* __restrict__ e_dst, int* __restrict__ deg)
{
    int e = blockIdx.x * blockDim.x + threadIdx.x;
    if (e < NEDGE) atomicAdd(&deg[e_dst[e]], 1);
}

// CSR build 2a: in-place per-block exclusive scan; block totals to bsum.
__global__ __launch_bounds__(256) void scan_block_kernel(
    int* __restrict__ data, int* __restrict__ bsum, int n)
{
    __shared__ int s[256];
    int t = threadIdx.x;
    int i = blockIdx.x * 256 + t;
    int v = (i < n) ? data[i] : 0;
    s[t] = v;
    __syncthreads();
    for (int o = 1; o < 256; o <<= 1) {
        int add = (t >= o) ? s[t - o] : 0;
        __syncthreads();
        s[t] += add;
        __syncthreads();
    }
    if (i < n) data[i] = s[t] - v;
    if (t == 255) bsum[blockIdx.x] = s[255];
}

// CSR build 2b: exclusive scan of block sums (single block).
__global__ __launch_bounds__(512) void scan_top_kernel(
    const int* __restrict__ bsum, int* __restrict__ bpre, int n)
{
    __shared__ int s[512];
    int t = threadIdx.x;
    int v = (t < n) ? bsum[t] : 0;
    s[t] = v;
    __syncthreads();
    for (int o = 1; o < 512; o <<= 1) {
        int add = (t >= o) ? s[t - o] : 0;
        __syncthreads();
        s[t] += add;
        __syncthreads();
    }
    if (t < n) bpre[t] = s[t] - v;
}

// CSR build 2c: add block prefix; copy to fill cursor.
__global__ __launch_bounds__(256) void scan_add_kernel(
    int* __restrict__ offs, int* __restrict__ cur,
    const int* __restrict__ bpre, int n)
{
    int i = blockIdx.x * 256 + threadIdx.x;
    if (i < n) {
        int o = offs[i] + bpre[blockIdx.x];
        offs[i] = o;
        cur[i] = o;
    }
}

// CSR build 3: place src ids into dst-grouped slots.
__global__ __launch_bounds__(256) void fill_kernel(
    const int* __restrict__ e_src, const int* __restrict__ e_dst,
    int* __restrict__ cur, int* __restrict__ csr)
{
    int e = blockIdx.x * blockDim.x + threadIdx.x;
    if (e < NEDGE) {
        int p = atomicAdd(&cur[e_dst[e]], 1);
        csr[p] = e_src[e];
    }
}

// Fused edge phase: per-dst softmax + weighted gather + relu. One wave per
// dst node. Fast path (deg <= 64, ~always: deg ~ Poisson(10)): scores live
// in registers, single gather of s_src. Feature accumulation: 16 lanes x
// float4 per edge, 4 edges in flight (sub = lane>>4). No atomics.
__global__ __launch_bounds__(256) void gather_kernel(
    const int* __restrict__ csr, const int* __restrict__ offs,
    const int* __restrict__ cur,
    const float* __restrict__ s_src, const float* __restrict__ s_dst,
    const float* __restrict__ z,
    float* __restrict__ txf)
{
    __shared__ int   se_s[4][64];
    __shared__ float w_s[4][64][4];
    int wslot = threadIdx.x >> 6;
    int dst = (blockIdx.x * blockDim.x + threadIdx.x) >> 6;
    if (dst >= N_TXN) return;
    int lane = threadIdx.x & 63;
    int r0 = offs[dst];
    int deg = cur[dst] - r0;

    float4 sd = *(const float4*)(s_dst + dst * 4);
    int f16 = lane & 15;
    int sub = lane >> 4;
    int h2 = f16 >> 2;

    float4 out4 = make_float4(0.f, 0.f, 0.f, 0.f);
    float4 den = make_float4(0.f, 0.f, 0.f, 0.f);

    if (deg <= 64) {
        // one edge per lane; scores stay in registers
        float4 a4 = make_float4(-1e30f, -1e30f, -1e30f, -1e30f);
        int s = 0;
        if (lane < deg) {
            s = csr[r0 + lane];
            float4 ss = *(const float4*)(s_src + s * 4);
            float a;
            a = ss.x + sd.x; a4.x = a >= 0.f ? a : 0.2f * a;
            a = ss.y + sd.y; a4.y = a >= 0.f ? a : 0.2f * a;
            a = ss.z + sd.z; a4.z = a >= 0.f ? a : 0.2f * a;
            a = ss.w + sd.w; a4.w = a >= 0.f ? a : 0.2f * a;
        }
        float4 mx = a4;
        #pragma unroll
        for (int o = 1; o < 64; o <<= 1) {
            mx.x = fmaxf(mx.x, __shfl_xor(mx.x, o));
            mx.y = fmaxf(mx.y, __shfl_xor(mx.y, o));
            mx.z = fmaxf(mx.z, __shfl_xor(mx.z, o));
            mx.w = fmaxf(mx.w, __shfl_xor(mx.w, o));
        }
        float4 w = make_float4(0.f, 0.f, 0.f, 0.f);
        if (lane < deg) {
            w.x = __expf(a4.x - mx.x);
            w.y = __expf(a4.y - mx.y);
            w.z = __expf(a4.z - mx.z);
            w.w = __expf(a4.w - mx.w);
            den = w;
        }
        se_s[wslot][lane] = s;
        *(float4*)(&w_s[wslot][lane][0]) = w;
        #pragma unroll
        for (int o = 1; o < 64; o <<= 1) {
            den.x += __shfl_xor(den.x, o);
            den.y += __shfl_xor(den.y, o);
            den.z += __shfl_xor(den.z, o);
            den.w += __shfl_xor(den.w, o);
        }
        for (int ee0 = 0; ee0 < deg; ee0 += 4) {
            int ee = ee0 + sub;
            if (ee < deg) {
                int se = se_s[wslot][ee];
                float wl = w_s[wslot][ee][h2];
                float4 zz = *(const float4*)(z + (size_t)se * 64 + f16 * 4);
                out4.x += zz.x * wl; out4.y += zz.y * wl;
                out4.z += zz.z * wl; out4.w += zz.w * wl;
            }
        }
    } else {
        // chunked fallback (rare): pass 1 max, pass 2 exp+gather
        float4 mx = make_float4(-1e30f, -1e30f, -1e30f, -1e30f);
        for (int base = 0; base < deg; base += 64) {
            int e = base + lane;
            if (e < deg) {
                int s = csr[r0 + e];
                float4 ss = *(const float4*)(s_src + s * 4);
                float a;
                a = ss.x + sd.x; a = a >= 0.f ? a : 0.2f * a; mx.x = fmaxf(mx.x, a);
                a = ss.y + sd.y; a = a >= 0.f ? a : 0.2f * a; mx.y = fmaxf(mx.y, a);
                a = ss.z + sd.z; a = a >= 0.f ? a : 0.2f * a; mx.z = fmaxf(mx.z, a);
                a = ss.w + sd.w; a = a >= 0.f ? a : 0.2f * a; mx.w = fmaxf(mx.w, a);
            }
        }
        #pragma unroll
        for (int o = 1; o < 64; o <<= 1) {
            mx.x = fmaxf(mx.x, __shfl_xor(mx.x, o));
            mx.y = fmaxf(mx.y, __shfl_xor(mx.y, o));
            mx.z = fmaxf(mx.z, __shfl_xor(mx.z, o));
            mx.w = fmaxf(mx.w, __shfl_xor(mx.w, o));
        }
        for (int base = 0; base < deg; base += 64) {
            int e = base + lane;
            int s = 0;
            float4 w = make_float4(0.f, 0.f, 0.f, 0.f);
            if (e < deg) {
                s = csr[r0 + e];
                float4 ss = *(const float4*)(s_src + s * 4);
                float a;
                a = ss.x + sd.x; a = a >= 0.f ? a : 0.2f * a; w.x = __expf(a - mx.x);
                a = ss.y + sd.y; a = a >= 0.f ? a : 0.2f * a; w.y = __expf(a - mx.y);
                a = ss.z + sd.z; a = a >= 0.f ? a : 0.2f * a; w.z = __expf(a - mx.z);
                a = ss.w + sd.w; a = a >= 0.f ? a : 0.2f * a; w.w = __expf(a - mx.w);
                den.x += w.x; den.y += w.y; den.z += w.z; den.w += w.w;
            }
            se_s[wslot][lane] = s;
            *(float4*)(&w_s[wslot][lane][0]) = w;
            int cnt = deg - base; if (cnt > 64) cnt = 64;
            for (int ee0 = 0; ee0 < cnt; ee0 += 4) {
                int ee = ee0 + sub;
                if (ee < cnt) {
                    int se = se_s[wslot][ee];
                    float wl = w_s[wslot][ee][h2];
                    float4 zz = *(const float4*)(z + (size_t)se * 64 + f16 * 4);
                    out4.x += zz.x * wl; out4.y += zz.y * wl;
                    out4.z += zz.z * wl; out4.w += zz.w * wl;
                }
            }
        }
        #pragma unroll
        for (int o = 1; o < 64; o <<= 1) {
            den.x += __shfl_xor(den.x, o);
            den.y += __shfl_xor(den.y, o);
            den.z += __shfl_xor(den.z, o);
            den.w += __shfl_xor(den.w, o);
        }
    }

    // combine the 4 edge-subset partials (sub dimension = lane bits 4..5)
    out4.x += __shfl_xor(out4.x, 16); out4.x += __shfl_xor(out4.x, 32);
    out4.y += __shfl_xor(out4.y, 16); out4.y += __shfl_xor(out4.y, 32);
    out4.z += __shfl_xor(out4.z, 16); out4.z += __shfl_xor(out4.z, 32);
    out4.w += __shfl_xor(out4.w, 16); out4.w += __shfl_xor(out4.w, 32);

    float denh = (h2 == 0) ? den.x : (h2 == 1) ? den.y : (h2 == 2) ? den.z : den.w;
    if (sub == 0) {
        float inv = 1.0f / (denh + 1e-16f);
        float4 r;
        r.x = fmaxf(out4.x * inv, 0.f);
        r.y = fmaxf(out4.y * inv, 0.f);
        r.z = fmaxf(out4.z * inv, 0.f);
        r.w = fmaxf(out4.w * inv, 0.f);
        ((float4*)(txf + (size_t)dst * 64))[f16] = r;
    }
}

// Mean-pool by (sorted) batch id; run-accumulate before one atomic per run.
#define POOL_CH 16
__global__ __launch_bounds__(256) void pool_kernel(
    const float* __restrict__ txf, const int* __restrict__ batch,
    float* __restrict__ g, float* __restrict__ cnt)
{
    int tid = blockIdx.x * blockDim.x + threadIdx.x;
    int chunk = tid >> 6;
    int d = tid & 63;
    int n0 = chunk * POOL_CH;
    if (n0 >= N_TXN) return;
    int n1 = n0 + POOL_CH; if (n1 > N_TXN) n1 = N_TXN;

    float run = 0.f, runc = 0.f;
    int cb = batch[n0];
    for (int node = n0; node < n1; ++node) {
        int b = batch[node];
        if (b != cb) {
            atomicAdd(&g[cb * 64 + d], run);
            if (d == 0) atomicAdd(&cnt[cb], runc);
            run = 0.f; runc = 0.f; cb = b;
        }
        run += txf[node * 64 + d];
        runc += 1.f;
    }
    atomicAdd(&g[cb * 64 + d], run);
    if (d == 0) atomicAdd(&cnt[cb], runc);
}

// Classifier: out = relu(gmean @ W1 + b1) @ W2 + b2. One block, 128 threads.
__global__ __launch_bounds__(128) void classifier_kernel(
    const float* __restrict__ g, const float* __restrict__ cnt,
    const float* __restrict__ W1, const float* __restrict__ b1,
    const float* __restrict__ W2, const float* __restrict__ b2,
    float* __restrict__ out)
{
    __shared__ float W1s[64 * 32];
    __shared__ float W2s[32];
    int t = threadIdx.x;
    for (int i = t; i < 64 * 32; i += 128) W1s[i] = W1[i];
    if (t < 32) W2s[t] = W2[t];
    __syncthreads();
    if (t >= NGRAPH) return;

    float c = fmaxf(cnt[t], 1.0f);
    float gm[64];
    #pragma unroll
    for (int k = 0; k < 64; ++k) gm[k] = g[t * 64 + k] / c;

    float o = b2[0];
    for (int j = 0; j < 32; ++j) {
        float acc = b1[j];
        #pragma unroll
        for (int k = 0; k < 64; ++k) acc += gm[k] * W1s[k * 32 + j];
        o += fmaxf(acc, 0.f) * W2s[j];
    }
    out[t] = o;
}

extern "C" void kernel_launch(void* const* d_in, const int* in_sizes, int n_in,
                              void* d_out, int out_size, void* d_ws, size_t ws_size,
                              hipStream_t stream)
{
    (void)in_sizes; (void)n_in; (void)out_size; (void)ws_size;

    const float* x_tx      = (const float*)d_in[0];
    const float* x_addr    = (const float*)d_in[1];
    const float* Wp_tx     = (const float*)d_in[2];
    const float* bp_tx     = (const float*)d_in[3];
    const float* Wp_ad     = (const float*)d_in[4];
    const float* bp_ad     = (const float*)d_in[5];
    const float* Wh_tx     = (const float*)d_in[6];
    const float* bh_tx     = (const float*)d_in[7];
    const float* Wh_ad     = (const float*)d_in[8];
    const float* bh_ad     = (const float*)d_in[9];
    // d_in[10],[11]: att_*_ta — dead (out_addr discarded by the reference)
    const float* att_src_at = (const float*)d_in[12];
    const float* att_dst_at = (const float*)d_in[13];
    // d_in[14..16]: W_k,b_k,q — dead (softmax over 1 metapath == identity)
    const float* W_c1      = (const float*)d_in[17];
    const float* b_c1      = (const float*)d_in[18];
    const float* W_c2      = (const float*)d_in[19];
    const float* b_c2      = (const float*)d_in[20];
    // d_in[21]: edge_ta — dead
    const int*   edge_at   = (const int*)d_in[22];   // [2, E] row-major
    const int*   batch_tx  = (const int*)d_in[23];

    float* ws    = (float*)d_ws;
    float* z_ad  = ws + OFF_Z;
    float* txf   = ws + OFF_TXF;
    float* s_src = ws + OFF_SS;
    float* s_dst = ws + OFF_SD;
    int*   csr   = (int*)ws + OFF_CSR;
    int*   offs  = (int*)ws + OFF_OFFS;
    int*   cur   = (int*)ws + OFF_CUR;
    int*   bsum  = (int*)ws + OFF_BSUM;
    int*   bpre  = (int*)ws + OFF_BPRE;
    float* g     = ws + OFF_G;
    float* cnt   = ws + OFF_CNT;

    const int* e_src = edge_at;          // addr ids (source)
    const int* e_dst = edge_at + NEDGE;  // tx ids (destination)

    init_kernel<<<(N_TXN + 255) / 256, 256, 0, stream>>>(ws);

    proj2_kernel<<<(N_ADDRN + PB - 1) / PB, 256, 0, stream>>>(
        x_addr, N_ADDRN, Wp_ad, bp_ad, Wh_ad, bh_ad, att_src_at, z_ad, s_src);
    proj2_kernel<<<(N_TXN + PB - 1) / PB, 256, 0, stream>>>(
        x_tx, N_TXN, Wp_tx, bp_tx, Wh_tx, bh_tx, att_dst_at, nullptr, s_dst);

    hist_kernel<<<(NEDGE + 255) / 256, 256, 0, stream>>>(e_dst, offs);
    scan_block_kernel<<<NBLK_SCAN, 256, 0, stream>>>(offs, bsum, N_TXN);
    scan_top_kernel<<<1, 512, 0, stream>>>(bsum, bpre, NBLK_SCAN);
    scan_add_kernel<<<NBLK_SCAN, 256, 0, stream>>>(offs, cur, bpre, N_TXN);
    fill_kernel<<<(NEDGE + 255) / 256, 256, 0, stream>>>(e_src, e_dst, cur, csr);

    gather_kernel<<<(N_TXN * 64) / 256, 256, 0, stream>>>(
        csr, offs, cur, s_src, s_dst, z_ad, txf);

    int nchunk = (N_TXN + POOL_CH - 1) / POOL_CH;
    pool_kernel<<<(nchunk * 64 + 255) / 256, 256, 0, stream>>>(
        txf, batch_tx, g, cnt);

    classifier_kernel<<<1, 128, 0, stream>>>(
        g, cnt, W_c1, b_c1, W_c2, b_c2, (float*)d_out);
}

// Round 7
// 413.826 us; speedup vs baseline: 4.0247x; 1.0380x over previous
//
#include <hip/hip_runtime.h>

// Problem constants (fixed by the reference)
#define N_TXN   100000
#define N_ADDRN 100000
#define NEDGE   1000000
#define NGRAPH  128
#define NBLK_SCAN ((N_TXN + 255) / 256)    // 391

// Workspace layout in 4-byte units
#define OFF_Z     0            // [N_ADDR*64] f32  z_addr features
#define OFF_TXF   6400000      // [N_TX*64]  f32  tx_feat (post relu/softmax)
#define OFF_SS    12800000     // [N_ADDR*4] f32  (z_addr . att_src_at)
#define OFF_SD    13200000     // [N_TX*4]   f32  (z_tx . att_dst_at)
#define OFF_CSR   13600000     // [E]        int  src ids grouped by dst
#define OFF_OFFS  14600000     // [N_TX]     int  deg -> exclusive offsets
#define OFF_CUR   14700000     // [N_TX]     int  fill cursor (ends = row end)
#define OFF_BSUM  14800000     // [512]      int  scan block sums
#define OFF_BPRE  14800512     // [512]      int  scan block prefixes
#define OFF_G     14801024     // [128*64]   f32  pooled graph sums
#define OFF_CNT   14809216     // [128]      f32  counts per graph

// dst-range partitioning (fill/gather XCD-locality): 8 groups x 12500 dsts
#define NGRP 8
#define DPG  12500
#define FILL_BLOCKS 1024       // multiple of 8

// Zero the regions that must start at 0: deg(offs), g, cnt.
__global__ void init_kernel(float* __restrict__ ws) {
    int i = blockIdx.x * blockDim.x + threadIdx.x;
    if (i < N_TXN) ((int*)ws)[OFF_OFFS + i] = 0;
    if (i < NGRAPH * 64) ws[OFF_G + i] = 0.0f;
    if (i < NGRAPH) ws[OFF_CNT + i] = 0.0f;
}

// Two-stage projection, NUMERICS MATCH REFERENCE STAGING:
//   h = x@Wp + bp  (rounded to f32)   then   z = h@Wh + bh
// (round-3 lesson: folding Wp@Wh reassociates past the bf16-level output
//  tolerance; summation-order changes are fine, stage-elimination is not.)
// Persistent grid-stride: weights staged ONCE per block (was once per 64
// nodes). 128 nodes/tile, 512 threads, each thread 4 nodes x 4 feats —
// per-node accumulation order identical to round 5 (bias-first, k asc).
#define PB 128
#define PT 512
__global__ __launch_bounds__(PT) void proj2_kernel(
    const float* __restrict__ x, int n_nodes,
    const float* __restrict__ Wp, const float* __restrict__ bp,
    const float* __restrict__ Wh, const float* __restrict__ bh,
    const float* __restrict__ att,      // 64 floats, flattened [H,D]
    float* __restrict__ z_out,          // may be nullptr (tx path)
    float* __restrict__ s_out)          // [n_nodes, 4]
{
    __shared__ float Wp_s[65 * 64];
    __shared__ float Wh_s[64 * 64];
    __shared__ float xh_s[PB * 68];     // x (65 used) then h (64 used)
    __shared__ float bp_s[64], bh_s[64], att_s[64];
    int t = threadIdx.x;

    for (int i = t; i < 65 * 64; i += PT) Wp_s[i] = Wp[i];
    for (int i = t; i < 64 * 64; i += PT) Wh_s[i] = Wh[i];
    if (t < 64) { bp_s[t] = bp[t]; bh_s[t] = bh[t]; att_s[t] = att[t]; }

    int ng = t >> 4;   // 32 node-groups x 4 nodes
    int fg = t & 15;   // float4 feature group
    const float4* Wpf = (const float4*)Wp_s;
    const float4* Whf = (const float4*)Wh_s;

    int ntiles = (n_nodes + PB - 1) / PB;
    for (int tile = blockIdx.x; tile < ntiles; tile += gridDim.x) {
        __syncthreads();    // weights ready / previous tile's xh_s reads done
        int nb = tile * PB;
        int nrem = n_nodes - nb; if (nrem > PB) nrem = PB;
        int tot = nrem * 65;
        for (int i = t; i < tot; i += PT) {
            int n = i / 65, k = i - n * 65;
            xh_s[n * 68 + k] = x[(size_t)nb * 65 + i];
        }
        __syncthreads();

        // stage 1: h = x@Wp + bp
        float4 acc[4];
        float4 b4 = ((const float4*)bp_s)[fg];
        #pragma unroll
        for (int i = 0; i < 4; ++i) acc[i] = b4;
        for (int k = 0; k < 65; ++k) {
            float4 w = Wpf[k * 16 + fg];
            #pragma unroll
            for (int i = 0; i < 4; ++i) {
                float xv = xh_s[(ng * 4 + i) * 68 + k];
                acc[i].x += xv * w.x; acc[i].y += xv * w.y;
                acc[i].z += xv * w.z; acc[i].w += xv * w.w;
            }
        }
        __syncthreads();    // all x reads done before overwrite
        #pragma unroll
        for (int i = 0; i < 4; ++i)
            *(float4*)(&xh_s[(ng * 4 + i) * 68 + fg * 4]) = acc[i];
        __syncthreads();    // h visible to all

        // stage 2: z = h@Wh + bh
        b4 = ((const float4*)bh_s)[fg];
        #pragma unroll
        for (int i = 0; i < 4; ++i) acc[i] = b4;
        for (int k = 0; k < 64; ++k) {
            float4 w = Whf[k * 16 + fg];
            #pragma unroll
            for (int i = 0; i < 4; ++i) {
                float hv = xh_s[(ng * 4 + i) * 68 + k];
                acc[i].x += hv * w.x; acc[i].y += hv * w.y;
                acc[i].z += hv * w.z; acc[i].w += hv * w.w;
            }
        }

        // epilogue: optional z store + per-head att dot
        float a0 = att_s[fg * 4], a1 = att_s[fg * 4 + 1];
        float a2 = att_s[fg * 4 + 2], a3 = att_s[fg * 4 + 3];
        #pragma unroll
        for (int i = 0; i < 4; ++i) {
            int n = ng * 4 + i;
            if (z_out && n < nrem)
                ((float4*)(z_out + (size_t)(nb + n) * 64))[fg] = acc[i];
            float p = acc[i].x * a0 + acc[i].y * a1 + acc[i].z * a2 + acc[i].w * a3;
            p += __shfl_xor(p, 1);
            p += __shfl_xor(p, 2);
            if ((fg & 3) == 0 && n < nrem)
                s_out[(nb + n) * 4 + (fg >> 2)] = p;
        }
    }
}

// CSR build 1: per-dst degree histogram.
__global__ __launch_bounds__(256) void hist_kernel(
    const int* __restrict__ e_dst, int* __restrict__ deg)
{
    int e = blockIdx.x * blockDim.x + threadIdx.x;
    if (e < NEDGE) atomicAdd(&deg[e_dst[e]], 1);
}

// CSR build 2a: in-place per-block exclusive scan; block totals to bsum.
__global__ __launch_bounds__(256) void scan_block_kernel(
    int* __restrict__ data, int* __restrict__ bsum, int n)
{
    __shared__ int s[256];
    int t = threadIdx.x;
    int i = blockIdx.x * 256 + t;
    int v = (i < n) ? data[i] : 0;
    s[t] = v;
    __syncthreads();
    for (int o = 1; o < 256; o <<= 1) {
        int add = (t >= o) ? s[t - o] : 0;
        __syncthreads();
        s[t] += add;
        __syncthreads();
    }
    if (i < n) data[i] = s[t] - v;
    if (t == 255) bsum[blockIdx.x] = s[255];
}

// CSR build 2b: exclusive scan of block sums (single block).
__global__ __launch_bounds__(512) void scan_top_kernel(
    const int* __restrict__ bsum, int* __restrict__ bpre, int n)
{
    __shared__ int s[512];
    int t = threadIdx.x;
    int v = (t < n) ? bsum[t] : 0;
    s[t] = v;
    __syncthreads();
    for (int o = 1; o < 512; o <<= 1) {
        int add = (t >= o) ? s[t - o] : 0;
        __syncthreads();
        s[t] += add;
        __syncthreads();
    }
    if (t < n) bpre[t] = s[t] - v;
}

// CSR build 2c: add block prefix; copy to fill cursor.
__global__ __launch_bounds__(256) void scan_add_kernel(
    int* __restrict__ offs, int* __restrict__ cur,
    const int* __restrict__ bpre, int n)
{
    int i = blockIdx.x * 256 + threadIdx.x;
    if (i < n) {
        int o = offs[i] + bpre[blockIdx.x];
        offs[i] = o;
        cur[i] = o;
    }
}

// CSR build 3: dst-range-partitioned scatter. Group g = blockIdx&7 owns
// dsts [g*DPG,(g+1)*DPG); each group collectively re-reads the whole edge
// list (coalesced) but writes ONLY its contiguous csr sub-region, so each
// 64B csr line is written by one XCD's blocks and coalesces in L2 instead
// of bouncing to HBM per 4B write (round-5: WRITE_SIZE 69MB for 4MB data).
__global__ __launch_bounds__(256) void fill_kernel(
    const int* __restrict__ e_src, const int* __restrict__ e_dst,
    int* __restrict__ cur, int* __restrict__ csr)
{
    int grp = blockIdx.x & (NGRP - 1);
    int sl  = blockIdx.x >> 3;
    const int NSL = FILL_BLOCKS / NGRP;            // slices per group
    const int per = (NEDGE + NSL - 1) / NSL;       // edges per slice
    int e0 = sl * per;
    int e1 = e0 + per; if (e1 > NEDGE) e1 = NEDGE;
    int lo = grp * DPG, hi = lo + DPG;
    for (int e = e0 + threadIdx.x; e < e1; e += 256) {
        int d = e_dst[e];
        if (d >= lo && d < hi) {
            int p = atomicAdd(&cur[d], 1);
            csr[p] = e_src[e];
        }
    }
}

// Fused edge phase: per-dst softmax + weighted gather + relu. One wave per
// dst node, dst assignment swizzled to match fill's grouping (blockIdx&7 →
// same dst range → csr reads hit the XCD-local L2 fill just wrote).
// Fast path (deg <= 64, ~always: deg ~ Poisson(10)): scores in registers.
// Feature accumulation: 16 lanes x float4 per edge, 4 edges in flight.
__global__ __launch_bounds__(256) void gather_kernel(
    const int* __restrict__ csr, const int* __restrict__ offs,
    const int* __restrict__ cur,
    const float* __restrict__ s_src, const float* __restrict__ s_dst,
    const float* __restrict__ z,
    float* __restrict__ txf)
{
    __shared__ int   se_s[4][64];
    __shared__ float w_s[4][64][4];
    int wslot = threadIdx.x >> 6;
    int grp = blockIdx.x & (NGRP - 1);
    int li  = (blockIdx.x >> 3) * 4 + wslot;       // [0, DPG)
    if (li >= DPG) return;
    int dst = grp * DPG + li;
    int lane = threadIdx.x & 63;
    int r0 = offs[dst];
    int deg = cur[dst] - r0;

    float4 sd = *(const float4*)(s_dst + dst * 4);
    int f16 = lane & 15;
    int sub = lane >> 4;
    int h2 = f16 >> 2;

    float4 out4 = make_float4(0.f, 0.f, 0.f, 0.f);
    float4 den = make_float4(0.f, 0.f, 0.f, 0.f);

    if (deg <= 64) {
        // one edge per lane; scores stay in registers
        float4 a4 = make_float4(-1e30f, -1e30f, -1e30f, -1e30f);
        int s = 0;
        if (lane < deg) {
            s = csr[r0 + lane];
            float4 ss = *(const float4*)(s_src + s * 4);
            float a;
            a = ss.x + sd.x; a4.x = a >= 0.f ? a : 0.2f * a;
            a = ss.y + sd.y; a4.y = a >= 0.f ? a : 0.2f * a;
            a = ss.z + sd.z; a4.z = a >= 0.f ? a : 0.2f * a;
            a = ss.w + sd.w; a4.w = a >= 0.f ? a : 0.2f * a;
        }
        float4 mx = a4;
        #pragma unroll
        for (int o = 1; o < 64; o <<= 1) {
            mx.x = fmaxf(mx.x, __shfl_xor(mx.x, o));
            mx.y = fmaxf(mx.y, __shfl_xor(mx.y, o));
            mx.z = fmaxf(mx.z, __shfl_xor(mx.z, o));
            mx.w = fmaxf(mx.w, __shfl_xor(mx.w, o));
        }
        float4 w = make_float4(0.f, 0.f, 0.f, 0.f);
        if (lane < deg) {
            w.x = __expf(a4.x - mx.x);
            w.y = __expf(a4.y - mx.y);
            w.z = __expf(a4.z - mx.z);
            w.w = __expf(a4.w - mx.w);
            den = w;
        }
        se_s[wslot][lane] = s;
        *(float4*)(&w_s[wslot][lane][0]) = w;
        #pragma unroll
        for (int o = 1; o < 64; o <<= 1) {
            den.x += __shfl_xor(den.x, o);
            den.y += __shfl_xor(den.y, o);
            den.z += __shfl_xor(den.z, o);
            den.w += __shfl_xor(den.w, o);
        }
        for (int ee0 = 0; ee0 < deg; ee0 += 4) {
            int ee = ee0 + sub;
            if (ee < deg) {
                int se = se_s[wslot][ee];
                float wl = w_s[wslot][ee][h2];
                float4 zz = *(const float4*)(z + (size_t)se * 64 + f16 * 4);
                out4.x += zz.x * wl; out4.y += zz.y * wl;
                out4.z += zz.z * wl; out4.w += zz.w * wl;
            }
        }
    } else {
        // chunked fallback (rare): pass 1 max, pass 2 exp+gather
        float4 mx = make_float4(-1e30f, -1e30f, -1e30f, -1e30f);
        for (int base = 0; base < deg; base += 64) {
            int e = base + lane;
            if (e < deg) {
                int s = csr[r0 + e];
                float4 ss = *(const float4*)(s_src + s * 4);
                float a;
                a = ss.x + sd.x; a = a >= 0.f ? a : 0.2f * a; mx.x = fmaxf(mx.x, a);
                a = ss.y + sd.y; a = a >= 0.f ? a : 0.2f * a; mx.y = fmaxf(mx.y, a);
                a = ss.z + sd.z; a = a >= 0.f ? a : 0.2f * a; mx.z = fmaxf(mx.z, a);
                a = ss.w + sd.w; a = a >= 0.f ? a : 0.2f * a; mx.w = fmaxf(mx.w, a);
            }
        }
        #pragma unroll
        for (int o = 1; o < 64; o <<= 1) {
            mx.x = fmaxf(mx.x, __shfl_xor(mx.x, o));
            mx.y = fmaxf(mx.y, __shfl_xor(mx.y, o));
            mx.z = fmaxf(mx.z, __shfl_xor(mx.z, o));
            mx.w = fmaxf(mx.w, __shfl_xor(mx.w, o));
        }
        for (int base = 0; base < deg; base += 64) {
            int e = base + lane;
            int s = 0;
            float4 w = make_float4(0.f, 0.f, 0.f, 0.f);
            if (e < deg) {
                s = csr[r0 + e];
                float4 ss = *(const float4*)(s_src + s * 4);
                float a;
                a = ss.x + sd.x; a = a >= 0.f ? a : 0.2f * a; w.x = __expf(a - mx.x);
                a = ss.y + sd.y; a = a >= 0.f ? a : 0.2f * a; w.y = __expf(a - mx.y);
                a = ss.z + sd.z; a = a >= 0.f ? a : 0.2f * a; w.z = __expf(a - mx.z);
                a = ss.w + sd.w; a = a >= 0.f ? a : 0.2f * a; w.w = __expf(a - mx.w);
                den.x += w.x; den.y += w.y; den.z += w.z; den.w += w.w;
            }
            se_s[wslot][lane] = s;
            *(float4*)(&w_s[wslot][lane][0]) = w;
            int cnt = deg - base; if (cnt > 64) cnt = 64;
            for (int ee0 = 0; ee0 < cnt; ee0 += 4) {
                int ee = ee0 + sub;
                if (ee < cnt) {
                    int se = se_s[wslot][ee];
                    float wl = w_s[wslot][ee][h2];
                    float4 zz = *(const float4*)(z + (size_t)se * 64 + f16 * 4);
                    out4.x += zz.x * wl; out4.y += zz.y * wl;
                    out4.z += zz.z * wl; out4.w += zz.w * wl;
                }
            }
        }
        #pragma unroll
        for (int o = 1; o < 64; o <<= 1) {
            den.x += __shfl_xor(den.x, o);
            den.y += __shfl_xor(den.y, o);
            den.z += __shfl_xor(den.z, o);
            den.w += __shfl_xor(den.w, o);
        }
    }

    // combine the 4 edge-subset partials (sub dimension = lane bits 4..5)
    out4.x += __shfl_xor(out4.x, 16); out4.x += __shfl_xor(out4.x, 32);
    out4.y += __shfl_xor(out4.y, 16); out4.y += __shfl_xor(out4.y, 32);
    out4.z += __shfl_xor(out4.z, 16); out4.z += __shfl_xor(out4.z, 32);
    out4.w += __shfl_xor(out4.w, 16); out4.w += __shfl_xor(out4.w, 32);

    float denh = (h2 == 0) ? den.x : (h2 == 1) ? den.y : (h2 == 2) ? den.z : den.w;
    if (sub == 0) {
        float inv = 1.0f / (denh + 1e-16f);
        float4 r;
        r.x = fmaxf(out4.x * inv, 0.f);
        r.y = fmaxf(out4.y * inv, 0.f);
        r.z = fmaxf(out4.z * inv, 0.f);
        r.w = fmaxf(out4.w * inv, 0.f);
        ((float4*)(txf + (size_t)dst * 64))[f16] = r;
    }
}

// Mean-pool by (sorted) batch id; run-accumulate before one atomic per run.
#define POOL_CH 16
__global__ __launch_bounds__(256) void pool_kernel(
    const float* __restrict__ txf, const int* __restrict__ batch,
    float* __restrict__ g, float* __restrict__ cnt)
{
    int tid = blockIdx.x * blockDim.x + threadIdx.x;
    int chunk = tid >> 6;
    int d = tid & 63;
    int n0 = chunk * POOL_CH;
    if (n0 >= N_TXN) return;
    int n1 = n0 + POOL_CH; if (n1 > N_TXN) n1 = N_TXN;

    float run = 0.f, runc = 0.f;
    int cb = batch[n0];
    for (int node = n0; node < n1; ++node) {
        int b = batch[node];
        if (b != cb) {
            atomicAdd(&g[cb * 64 + d], run);
            if (d == 0) atomicAdd(&cnt[cb], runc);
            run = 0.f; runc = 0.f; cb = b;
        }
        run += txf[node * 64 + d];
        runc += 1.f;
    }
    atomicAdd(&g[cb * 64 + d], run);
    if (d == 0) atomicAdd(&cnt[cb], runc);
}

// Classifier: out = relu(gmean @ W1 + b1) @ W2 + b2. One block, 128 threads.
__global__ __launch_bounds__(128) void classifier_kernel(
    const float* __restrict__ g, const float* __restrict__ cnt,
    const float* __restrict__ W1, const float* __restrict__ b1,
    const float* __restrict__ W2, const float* __restrict__ b2,
    float* __restrict__ out)
{
    __shared__ float W1s[64 * 32];
    __shared__ float W2s[32];
    int t = threadIdx.x;
    for (int i = t; i < 64 * 32; i += 128) W1s[i] = W1[i];
    if (t < 32) W2s[t] = W2[t];
    __syncthreads();
    if (t >= NGRAPH) return;

    float c = fmaxf(cnt[t], 1.0f);
    float gm[64];
    #pragma unroll
    for (int k = 0; k < 64; ++k) gm[k] = g[t * 64 + k] / c;

    float o = b2[0];
    for (int j = 0; j < 32; ++j) {
        float acc = b1[j];
        #pragma unroll
        for (int k = 0; k < 64; ++k) acc += gm[k] * W1s[k * 32 + j];
        o += fmaxf(acc, 0.f) * W2s[j];
    }
    out[t] = o;
}

extern "C" void kernel_launch(void* const* d_in, const int* in_sizes, int n_in,
                              void* d_out, int out_size, void* d_ws, size_t ws_size,
                              hipStream_t stream)
{
    (void)in_sizes; (void)n_in; (void)out_size; (void)ws_size;

    const float* x_tx      = (const float*)d_in[0];
    const float* x_addr    = (const float*)d_in[1];
    const float* Wp_tx     = (const float*)d_in[2];
    const float* bp_tx     = (const float*)d_in[3];
    const float* Wp_ad     = (const float*)d_in[4];
    const float* bp_ad     = (const float*)d_in[5];
    const float* Wh_tx     = (const float*)d_in[6];
    const float* bh_tx     = (const float*)d_in[7];
    const float* Wh_ad     = (const float*)d_in[8];
    const float* bh_ad     = (const float*)d_in[9];
    // d_in[10],[11]: att_*_ta — dead (out_addr discarded by the reference)
    const float* att_src_at = (const float*)d_in[12];
    const float* att_dst_at = (const float*)d_in[13];
    // d_in[14..16]: W_k,b_k,q — dead (softmax over 1 metapath == identity)
    const float* W_c1      = (const float*)d_in[17];
    const float* b_c1      = (const float*)d_in[18];
    const float* W_c2      = (const float*)d_in[19];
    const float* b_c2      = (const float*)d_in[20];
    // d_in[21]: edge_ta — dead
    const int*   edge_at   = (const int*)d_in[22];   // [2, E] row-major
    const int*   batch_tx  = (const int*)d_in[23];

    float* ws    = (float*)d_ws;
    float* z_ad  = ws + OFF_Z;
    float* txf   = ws + OFF_TXF;
    float* s_src = ws + OFF_SS;
    float* s_dst = ws + OFF_SD;
    int*   csr   = (int*)ws + OFF_CSR;
    int*   offs  = (int*)ws + OFF_OFFS;
    int*   cur   = (int*)ws + OFF_CUR;
    int*   bsum  = (int*)ws + OFF_BSUM;
    int*   bpre  = (int*)ws + OFF_BPRE;
    float* g     = ws + OFF_G;
    float* cnt   = ws + OFF_CNT;

    const int* e_src = edge_at;          // addr ids (source)
    const int* e_dst = edge_at + NEDGE;  // tx ids (destination)

    init_kernel<<<(N_TXN + 255) / 256, 256, 0, stream>>>(ws);

    proj2_kernel<<<512, PT, 0, stream>>>(
        x_addr, N_ADDRN, Wp_ad, bp_ad, Wh_ad, bh_ad, att_src_at, z_ad, s_src);
    proj2_kernel<<<512, PT, 0, stream>>>(
        x_tx, N_TXN, Wp_tx, bp_tx, Wh_tx, bh_tx, att_dst_at, nullptr, s_dst);

    hist_kernel<<<(NEDGE + 255) / 256, 256, 0, stream>>>(e_dst, offs);
    scan_block_kernel<<<NBLK_SCAN, 256, 0, stream>>>(offs, bsum, N_TXN);
    scan_top_kernel<<<1, 512, 0, stream>>>(bsum, bpre, NBLK_SCAN);
    scan_add_kernel<<<NBLK_SCAN, 256, 0, stream>>>(offs, cur, bpre, N_TXN);
    fill_kernel<<<FILL_BLOCKS, 256, 0, stream>>>(e_src, e_dst, cur, csr);

    // grid: 8 groups x 3125 blocks x 4 waves = 100000 dsts exactly
    gather_kernel<<<25000, 256, 0, stream>>>(
        csr, offs, cur, s_src, s_dst, z_ad, txf);

    int nchunk = (N_TXN + POOL_CH - 1) / POOL_CH;
    pool_kernel<<<(nchunk * 64 + 255) / 256, 256, 0, stream>>>(
        txf, batch_tx, g, cnt);

    classifier_kernel<<<1, 128, 0, stream>>>(
        g, cnt, W_c1, b_c1, W_c2, b_c2, (float*)d_out);
}

// Round 8
// 396.340 us; speedup vs baseline: 4.2023x; 1.0441x over previous
//
#include <hip/hip_runtime.h>

// Problem constants (fixed by the reference)
#define N_TXN   100000
#define N_ADDRN 100000
#define NEDGE   1000000
#define NGRAPH  128
#define NBLK_SCAN ((N_TXN + 255) / 256)    // 391

// Workspace layout in 4-byte units
#define OFF_Z     0            // [N_ADDR*64] f32  z_addr features
#define OFF_TXF   6400000      // [N_TX*64]  f32  tx_feat (post relu/softmax)
#define OFF_SS    12800000     // [N_ADDR*4] f32  (z_addr . att_src_at)
#define OFF_SD    13200000     // [N_TX*4]   f32  (z_tx . att_dst_at)
#define OFF_CSR   13600000     // [E]        int  src ids grouped by dst
#define OFF_OFFS  14600000     // [N_TX]     int  deg -> exclusive offsets
#define OFF_CUR   14700000     // [N_TX]     int  fill cursor (ends = row end)
#define OFF_BSUM  14800000     // [512]      int  scan block sums
#define OFF_G     14801024     // [128*64]   f32  pooled graph sums
#define OFF_CNT   14809216     // [128]      f32  counts per graph

// dst-range partitioning (fill/gather XCD-locality): 8 groups x 12500 dsts
#define NGRP 8
#define DPG  12500
#define FILL_BLOCKS 1024       // multiple of 8

// Zero the regions that must start at 0: deg(offs), g, cnt.
__global__ void init_kernel(float* __restrict__ ws) {
    int i = blockIdx.x * blockDim.x + threadIdx.x;
    if (i < N_TXN) ((int*)ws)[OFF_OFFS + i] = 0;
    if (i < NGRAPH * 64) ws[OFF_G + i] = 0.0f;
    if (i < NGRAPH) ws[OFF_CNT + i] = 0.0f;
}

// Two-stage projection, NUMERICS MATCH REFERENCE STAGING:
//   h = x@Wp + bp  (rounded to f32)   then   z = h@Wh + bh
// (round-3 lesson: folding Wp@Wh reassociates past the bf16-level output
//  tolerance; summation-order changes are fine, stage-elimination is not.)
// Persistent grid-stride: weights staged ONCE per block. 128 nodes/tile,
// 512 threads, each thread 4 nodes x 4 feats; bias-first, k ascending.
#define PB 128
#define PT 512
__global__ __launch_bounds__(PT) void proj2_kernel(
    const float* __restrict__ x, int n_nodes,
    const float* __restrict__ Wp, const float* __restrict__ bp,
    const float* __restrict__ Wh, const float* __restrict__ bh,
    const float* __restrict__ att,      // 64 floats, flattened [H,D]
    float* __restrict__ z_out,          // may be nullptr (tx path)
    float* __restrict__ s_out)          // [n_nodes, 4]
{
    __shared__ float Wp_s[65 * 64];
    __shared__ float Wh_s[64 * 64];
    __shared__ float xh_s[PB * 68];     // x (65 used) then h (64 used)
    __shared__ float bp_s[64], bh_s[64], att_s[64];
    int t = threadIdx.x;

    for (int i = t; i < 65 * 64; i += PT) Wp_s[i] = Wp[i];
    for (int i = t; i < 64 * 64; i += PT) Wh_s[i] = Wh[i];
    if (t < 64) { bp_s[t] = bp[t]; bh_s[t] = bh[t]; att_s[t] = att[t]; }

    int ng = t >> 4;   // 32 node-groups x 4 nodes
    int fg = t & 15;   // float4 feature group
    const float4* Wpf = (const float4*)Wp_s;
    const float4* Whf = (const float4*)Wh_s;

    int ntiles = (n_nodes + PB - 1) / PB;
    for (int tile = blockIdx.x; tile < ntiles; tile += gridDim.x) {
        __syncthreads();    // weights ready / previous tile's xh_s reads done
        int nb = tile * PB;
        int nrem = n_nodes - nb; if (nrem > PB) nrem = PB;
        int tot = nrem * 65;
        for (int i = t; i < tot; i += PT) {
            int n = i / 65, k = i - n * 65;
            xh_s[n * 68 + k] = x[(size_t)nb * 65 + i];
        }
        __syncthreads();

        // stage 1: h = x@Wp + bp
        float4 acc[4];
        float4 b4 = ((const float4*)bp_s)[fg];
        #pragma unroll
        for (int i = 0; i < 4; ++i) acc[i] = b4;
        for (int k = 0; k < 65; ++k) {
            float4 w = Wpf[k * 16 + fg];
            #pragma unroll
            for (int i = 0; i < 4; ++i) {
                float xv = xh_s[(ng * 4 + i) * 68 + k];
                acc[i].x += xv * w.x; acc[i].y += xv * w.y;
                acc[i].z += xv * w.z; acc[i].w += xv * w.w;
            }
        }
        __syncthreads();    // all x reads done before overwrite
        #pragma unroll
        for (int i = 0; i < 4; ++i)
            *(float4*)(&xh_s[(ng * 4 + i) * 68 + fg * 4]) = acc[i];
        __syncthreads();    // h visible to all

        // stage 2: z = h@Wh + bh
        b4 = ((const float4*)bh_s)[fg];
        #pragma unroll
        for (int i = 0; i < 4; ++i) acc[i] = b4;
        for (int k = 0; k < 64; ++k) {
            float4 w = Whf[k * 16 + fg];
            #pragma unroll
            for (int i = 0; i < 4; ++i) {
                float hv = xh_s[(ng * 4 + i) * 68 + k];
                acc[i].x += hv * w.x; acc[i].y += hv * w.y;
                acc[i].z += hv * w.z; acc[i].w += hv * w.w;
            }
        }

        // epilogue: optional z store + per-head att dot
        float a0 = att_s[fg * 4], a1 = att_s[fg * 4 + 1];
        float a2 = att_s[fg * 4 + 2], a3 = att_s[fg * 4 + 3];
        #pragma unroll
        for (int i = 0; i < 4; ++i) {
            int n = ng * 4 + i;
            if (z_out && n < nrem)
                ((float4*)(z_out + (size_t)(nb + n) * 64))[fg] = acc[i];
            float p = acc[i].x * a0 + acc[i].y * a1 + acc[i].z * a2 + acc[i].w * a3;
            p += __shfl_xor(p, 1);
            p += __shfl_xor(p, 2);
            if ((fg & 3) == 0 && n < nrem)
                s_out[(nb + n) * 4 + (fg >> 2)] = p;
        }
    }
}

// CSR build 1: per-dst degree histogram.
__global__ __launch_bounds__(256) void hist_kernel(
    const int* __restrict__ e_dst, int* __restrict__ deg)
{
    int e = blockIdx.x * blockDim.x + threadIdx.x;
    if (e < NEDGE) atomicAdd(&deg[e_dst[e]], 1);
}

// CSR build 2a: in-place per-block exclusive scan; block totals to bsum.
__global__ __launch_bounds__(256) void scan_block_kernel(
    int* __restrict__ data, int* __restrict__ bsum, int n)
{
    __shared__ int s[256];
    int t = threadIdx.x;
    int i = blockIdx.x * 256 + t;
    int v = (i < n) ? data[i] : 0;
    s[t] = v;
    __syncthreads();
    for (int o = 1; o < 256; o <<= 1) {
        int add = (t >= o) ? s[t - o] : 0;
        __syncthreads();
        s[t] += add;
        __syncthreads();
    }
    if (i < n) data[i] = s[t] - v;
    if (t == 255) bsum[blockIdx.x] = s[255];
}

// CSR build 2b (fused top-scan + add): every 512-thread block redundantly
// scans the 391 block sums in LDS, then applies the prefix to its 512
// offs elements (chunk c = i>>8 selects the bsum prefix) and copies to cur.
__global__ __launch_bounds__(512) void scan_apply_kernel(
    int* __restrict__ offs, int* __restrict__ cur,
    const int* __restrict__ bsum, int n, int nb)
{
    __shared__ int pre_s[512];
    int t = threadIdx.x;
    int v = (t < nb) ? bsum[t] : 0;
    pre_s[t] = v;
    __syncthreads();
    for (int o = 1; o < 512; o <<= 1) {
        int add = (t >= o) ? pre_s[t - o] : 0;
        __syncthreads();
        pre_s[t] += add;
        __syncthreads();
    }
    pre_s[t] -= v;          // exclusive
    __syncthreads();
    int i = blockIdx.x * 512 + t;
    if (i < n) {
        int o = offs[i] + pre_s[i >> 8];
        offs[i] = o;
        cur[i] = o;
    }
}

// CSR build 3: dst-range-partitioned scatter (round-7 WIN: WRITE_SIZE fix).
// Group g = blockIdx&7 owns dsts [g*DPG,(g+1)*DPG); each group re-reads the
// whole edge list (coalesced) but writes ONLY its contiguous csr sub-region.
__global__ __launch_bounds__(256) void fill_kernel(
    const int* __restrict__ e_src, const int* __restrict__ e_dst,
    int* __restrict__ cur, int* __restrict__ csr)
{
    int grp = blockIdx.x & (NGRP - 1);
    int sl  = blockIdx.x >> 3;
    const int NSL = FILL_BLOCKS / NGRP;            // slices per group
    const int per = (NEDGE + NSL - 1) / NSL;       // edges per slice
    int e0 = sl * per;
    int e1 = e0 + per; if (e1 > NEDGE) e1 = NEDGE;
    int lo = grp * DPG, hi = lo + DPG;
    for (int e = e0 + threadIdx.x; e < e1; e += 256) {
        int d = e_dst[e];
        if (d >= lo && d < hi) {
            int p = atomicAdd(&cur[d], 1);
            csr[p] = e_src[e];
        }
    }
}

// Fused edge phase, 16-LANE GROUPS (4 dsts/wave, 16 dsts/block).
// Round-7 diagnosis: 64-lane-per-dst wasted 84% of scoring lanes and spent
// 48 shfl steps reducing ~10 values; only ~3 feature iterations per wave to
// hide random-256B z fetch latency. 16-lane groups cut reduction to 4 steps,
// idle lanes to ~38%, and put 4x more dsts in flight per wave.
// Fast path deg<=16 (97.4% of Poisson(10)); chunked two-pass fallback else.
__global__ __launch_bounds__(256) void gather_kernel(
    const int* __restrict__ csr, const int* __restrict__ offs,
    const int* __restrict__ cur,
    const float* __restrict__ s_src, const float* __restrict__ s_dst,
    const float* __restrict__ z,
    float* __restrict__ txf)
{
    __shared__ int   se_s[16][16];
    __shared__ float w_s[16][16][4];
    int grpId = threadIdx.x >> 4;       // 16 groups per block
    int l16 = threadIdx.x & 15;
    int grp = blockIdx.x & (NGRP - 1);
    int li  = (blockIdx.x >> 3) * 16 + grpId;      // [0, 12512)
    if (li >= DPG) return;
    int dst = grp * DPG + li;
    int r0 = offs[dst];
    int deg = cur[dst] - r0;
    int h = l16 >> 2;                   // head for this lane's 4 features

    float4 sd = *(const float4*)(s_dst + dst * 4);
    float4 outA = make_float4(0.f, 0.f, 0.f, 0.f);
    float4 outB = make_float4(0.f, 0.f, 0.f, 0.f);
    float4 den = make_float4(0.f, 0.f, 0.f, 0.f);

    if (deg <= 16) {
        // one edge per lane; scores in registers; single pass
        float4 a4 = make_float4(-1e30f, -1e30f, -1e30f, -1e30f);
        int s = 0;
        if (l16 < deg) {
            s = csr[r0 + l16];
            float4 ss = *(const float4*)(s_src + s * 4);
            float a;
            a = ss.x + sd.x; a4.x = a >= 0.f ? a : 0.2f * a;
            a = ss.y + sd.y; a4.y = a >= 0.f ? a : 0.2f * a;
            a = ss.z + sd.z; a4.z = a >= 0.f ? a : 0.2f * a;
            a = ss.w + sd.w; a4.w = a >= 0.f ? a : 0.2f * a;
        }
        float4 mx = a4;
        #pragma unroll
        for (int o = 1; o < 16; o <<= 1) {
            mx.x = fmaxf(mx.x, __shfl_xor(mx.x, o));
            mx.y = fmaxf(mx.y, __shfl_xor(mx.y, o));
            mx.z = fmaxf(mx.z, __shfl_xor(mx.z, o));
            mx.w = fmaxf(mx.w, __shfl_xor(mx.w, o));
        }
        float4 w = make_float4(0.f, 0.f, 0.f, 0.f);
        if (l16 < deg) {
            w.x = __expf(a4.x - mx.x);
            w.y = __expf(a4.y - mx.y);
            w.z = __expf(a4.z - mx.z);
            w.w = __expf(a4.w - mx.w);
            den = w;
        }
        se_s[grpId][l16] = s;
        *(float4*)(&w_s[grpId][l16][0]) = w;
        #pragma unroll
        for (int o = 1; o < 16; o <<= 1) {
            den.x += __shfl_xor(den.x, o);
            den.y += __shfl_xor(den.y, o);
            den.z += __shfl_xor(den.z, o);
            den.w += __shfl_xor(den.w, o);
        }
        // feature accumulation, 2-way unrolled (two accumulators)
        int ee = 0;
        for (; ee + 1 < deg; ee += 2) {
            int sa = se_s[grpId][ee];
            int sb = se_s[grpId][ee + 1];
            float wa = w_s[grpId][ee][h];
            float wb = w_s[grpId][ee + 1][h];
            float4 za = *(const float4*)(z + (size_t)sa * 64 + l16 * 4);
            float4 zb = *(const float4*)(z + (size_t)sb * 64 + l16 * 4);
            outA.x += za.x * wa; outA.y += za.y * wa;
            outA.z += za.z * wa; outA.w += za.w * wa;
            outB.x += zb.x * wb; outB.y += zb.y * wb;
            outB.z += zb.z * wb; outB.w += zb.w * wb;
        }
        if (ee < deg) {
            int sa = se_s[grpId][ee];
            float wa = w_s[grpId][ee][h];
            float4 za = *(const float4*)(z + (size_t)sa * 64 + l16 * 4);
            outA.x += za.x * wa; outA.y += za.y * wa;
            outA.z += za.z * wa; outA.w += za.w * wa;
        }
    } else {
        // chunked two-pass fallback (deg > 16, ~2.6%)
        float4 mx = make_float4(-1e30f, -1e30f, -1e30f, -1e30f);
        for (int base = 0; base < deg; base += 16) {
            if (base + l16 < deg) {
                int s = csr[r0 + base + l16];
                float4 ss = *(const float4*)(s_src + s * 4);
                float a;
                a = ss.x + sd.x; a = a >= 0.f ? a : 0.2f * a; mx.x = fmaxf(mx.x, a);
                a = ss.y + sd.y; a = a >= 0.f ? a : 0.2f * a; mx.y = fmaxf(mx.y, a);
                a = ss.z + sd.z; a = a >= 0.f ? a : 0.2f * a; mx.z = fmaxf(mx.z, a);
                a = ss.w + sd.w; a = a >= 0.f ? a : 0.2f * a; mx.w = fmaxf(mx.w, a);
            }
        }
        #pragma unroll
        for (int o = 1; o < 16; o <<= 1) {
            mx.x = fmaxf(mx.x, __shfl_xor(mx.x, o));
            mx.y = fmaxf(mx.y, __shfl_xor(mx.y, o));
            mx.z = fmaxf(mx.z, __shfl_xor(mx.z, o));
            mx.w = fmaxf(mx.w, __shfl_xor(mx.w, o));
        }
        for (int base = 0; base < deg; base += 16) {
            int cnt = deg - base; if (cnt > 16) cnt = 16;
            int s = 0;
            float4 w = make_float4(0.f, 0.f, 0.f, 0.f);
            if (l16 < cnt) {
                s = csr[r0 + base + l16];
                float4 ss = *(const float4*)(s_src + s * 4);
                float a;
                a = ss.x + sd.x; a = a >= 0.f ? a : 0.2f * a; w.x = __expf(a - mx.x);
                a = ss.y + sd.y; a = a >= 0.f ? a : 0.2f * a; w.y = __expf(a - mx.y);
                a = ss.z + sd.z; a = a >= 0.f ? a : 0.2f * a; w.z = __expf(a - mx.z);
                a = ss.w + sd.w; a = a >= 0.f ? a : 0.2f * a; w.w = __expf(a - mx.w);
                den.x += w.x; den.y += w.y; den.z += w.z; den.w += w.w;
            }
            se_s[grpId][l16] = s;
            *(float4*)(&w_s[grpId][l16][0]) = w;
            for (int ee = 0; ee < cnt; ++ee) {
                int se = se_s[grpId][ee];
                float wl = w_s[grpId][ee][h];
                float4 zz = *(const float4*)(z + (size_t)se * 64 + l16 * 4);
                outA.x += zz.x * wl; outA.y += zz.y * wl;
                outA.z += zz.z * wl; outA.w += zz.w * wl;
            }
        }
        #pragma unroll
        for (int o = 1; o < 16; o <<= 1) {
            den.x += __shfl_xor(den.x, o);
            den.y += __shfl_xor(den.y, o);
            den.z += __shfl_xor(den.z, o);
            den.w += __shfl_xor(den.w, o);
        }
    }

    float denh = (h == 0) ? den.x : (h == 1) ? den.y : (h == 2) ? den.z : den.w;
    float inv = 1.0f / (denh + 1e-16f);
    float4 r;
    r.x = fmaxf((outA.x + outB.x) * inv, 0.f);
    r.y = fmaxf((outA.y + outB.y) * inv, 0.f);
    r.z = fmaxf((outA.z + outB.z) * inv, 0.f);
    r.w = fmaxf((outA.w + outB.w) * inv, 0.f);
    ((float4*)(txf + (size_t)dst * 64))[l16] = r;
}

// Mean-pool by (sorted) batch id; run-accumulate before one atomic per run.
#define POOL_CH 16
__global__ __launch_bounds__(256) void pool_kernel(
    const float* __restrict__ txf, const int* __restrict__ batch,
    float* __restrict__ g, float* __restrict__ cnt)
{
    int tid = blockIdx.x * blockDim.x + threadIdx.x;
    int chunk = tid >> 6;
    int d = tid & 63;
    int n0 = chunk * POOL_CH;
    if (n0 >= N_TXN) return;
    int n1 = n0 + POOL_CH; if (n1 > N_TXN) n1 = N_TXN;

    float run = 0.f, runc = 0.f;
    int cb = batch[n0];
    for (int node = n0; node < n1; ++node) {
        int b = batch[node];
        if (b != cb) {
            atomicAdd(&g[cb * 64 + d], run);
            if (d == 0) atomicAdd(&cnt[cb], runc);
            run = 0.f; runc = 0.f; cb = b;
        }
        run += txf[node * 64 + d];
        runc += 1.f;
    }
    atomicAdd(&g[cb * 64 + d], run);
    if (d == 0) atomicAdd(&cnt[cb], runc);
}

// Classifier: out = relu(gmean @ W1 + b1) @ W2 + b2. One block, 128 threads.
__global__ __launch_bounds__(128) void classifier_kernel(
    const float* __restrict__ g, const float* __restrict__ cnt,
    const float* __restrict__ W1, const float* __restrict__ b1,
    const float* __restrict__ W2, const float* __restrict__ b2,
    float* __restrict__ out)
{
    __shared__ float W1s[64 * 32];
    __shared__ float W2s[32];
    int t = threadIdx.x;
    for (int i = t; i < 64 * 32; i += 128) W1s[i] = W1[i];
    if (t < 32) W2s[t] = W2[t];
    __syncthreads();
    if (t >= NGRAPH) return;

    float c = fmaxf(cnt[t], 1.0f);
    float gm[64];
    #pragma unroll
    for (int k = 0; k < 64; ++k) gm[k] = g[t * 64 + k] / c;

    float o = b2[0];
    for (int j = 0; j < 32; ++j) {
        float acc = b1[j];
        #pragma unroll
        for (int k = 0; k < 64; ++k) acc += gm[k] * W1s[k * 32 + j];
        o += fmaxf(acc, 0.f) * W2s[j];
    }
    out[t] = o;
}

extern "C" void kernel_launch(void* const* d_in, const int* in_sizes, int n_in,
                              void* d_out, int out_size, void* d_ws, size_t ws_size,
                              hipStream_t stream)
{
    (void)in_sizes; (void)n_in; (void)out_size; (void)ws_size;

    const float* x_tx      = (const float*)d_in[0];
    const float* x_addr    = (const float*)d_in[1];
    const float* Wp_tx     = (const float*)d_in[2];
    const float* bp_tx     = (const float*)d_in[3];
    const float* Wp_ad     = (const float*)d_in[4];
    const float* bp_ad     = (const float*)d_in[5];
    const float* Wh_tx     = (const float*)d_in[6];
    const float* bh_tx     = (const float*)d_in[7];
    const float* Wh_ad     = (const float*)d_in[8];
    const float* bh_ad     = (const float*)d_in[9];
    // d_in[10],[11]: att_*_ta — dead (out_addr discarded by the reference)
    const float* att_src_at = (const float*)d_in[12];
    const float* att_dst_at = (const float*)d_in[13];
    // d_in[14..16]: W_k,b_k,q — dead (softmax over 1 metapath == identity)
    const float* W_c1      = (const float*)d_in[17];
    const float* b_c1      = (const float*)d_in[18];
    const float* W_c2      = (const float*)d_in[19];
    const float* b_c2      = (const float*)d_in[20];
    // d_in[21]: edge_ta — dead
    const int*   edge_at   = (const int*)d_in[22];   // [2, E] row-major
    const int*   batch_tx  = (const int*)d_in[23];

    float* ws    = (float*)d_ws;
    float* z_ad  = ws + OFF_Z;
    float* txf   = ws + OFF_TXF;
    float* s_src = ws + OFF_SS;
    float* s_dst = ws + OFF_SD;
    int*   csr   = (int*)ws + OFF_CSR;
    int*   offs  = (int*)ws + OFF_OFFS;
    int*   cur   = (int*)ws + OFF_CUR;
    int*   bsum  = (int*)ws + OFF_BSUM;
    float* g     = ws + OFF_G;
    float* cnt   = ws + OFF_CNT;

    const int* e_src = edge_at;          // addr ids (source)
    const int* e_dst = edge_at + NEDGE;  // tx ids (destination)

    init_kernel<<<(N_TXN + 255) / 256, 256, 0, stream>>>(ws);

    proj2_kernel<<<512, PT, 0, stream>>>(
        x_addr, N_ADDRN, Wp_ad, bp_ad, Wh_ad, bh_ad, att_src_at, z_ad, s_src);
    proj2_kernel<<<512, PT, 0, stream>>>(
        x_tx, N_TXN, Wp_tx, bp_tx, Wh_tx, bh_tx, att_dst_at, nullptr, s_dst);

    hist_kernel<<<(NEDGE + 255) / 256, 256, 0, stream>>>(e_dst, offs);
    scan_block_kernel<<<NBLK_SCAN, 256, 0, stream>>>(offs, bsum, N_TXN);
    scan_apply_kernel<<<(N_TXN + 511) / 512, 512, 0, stream>>>(
        offs, cur, bsum, N_TXN, NBLK_SCAN);
    fill_kernel<<<FILL_BLOCKS, 256, 0, stream>>>(e_src, e_dst, cur, csr);

    // grid: 8 groups x 782 blocks x 16 dst-groups = 100096 slots (li guard)
    gather_kernel<<<8 * 782, 256, 0, stream>>>(
        csr, offs, cur, s_src, s_dst, z_ad, txf);

    int nchunk = (N_TXN + POOL_CH - 1) / POOL_CH;
    pool_kernel<<<(nchunk * 64 + 255) / 256, 256, 0, stream>>>(
        txf, batch_tx, g, cnt);

    classifier_kernel<<<1, 128, 0, stream>>>(
        g, cnt, W_c1, b_c1, W_c2, b_c2, (float*)d_out);
}

// Round 10
// 332.239 us; speedup vs baseline: 5.0130x; 1.1929x over previous
//
#include <hip/hip_runtime.h>

// Problem constants (fixed by the reference)
#define N_TXN   100000
#define N_ADDRN 100000
#define NEDGE   1000000
#define NGRAPH  128

// Dense-slot CSR: 24 slots/dst (P[Poisson(10) > 24] ~ 3e-5 -> overflow list)
#define DSLOT   24
#define OVF_CAP 2048

// Workspace layout in 4-byte units (total 9.71M floats = 38.9 MB, well under
// the 59.3 MB proven-safe bound of rounds 1-8; r9's 64.5 MB crashed and
// workspace overflow could not be ruled out)
#define OFF_Z     0            // [N_ADDR*64] f32  z_addr features
#define OFF_SS    6400000      // [N_ADDR*4] f32  (z_addr . att_src_at)
#define OFF_SD    6800000      // [N_TX*4]   f32  (z_tx . att_dst_at)
#define OFF_CSRD  7200000      // [N_TX*24]  int  dense src slots
#define OFF_CUR   9600000      // [N_TX]     int  per-dst edge count
#define OFF_OVFC  9700000      // [64]       int  overflow counter
#define OFF_OVF   9700064      // [2*OVF_CAP]int  overflow (dst,src) pairs
#define OFF_G     9704160      // [128*64]   f32  pooled graph sums
#define OFF_CNT   9712352      // [128]      f32  counts per graph

// dst-range partitioning (fill/gather XCD-locality): 8 groups x 12500 dsts
#define NGRP 8
#define DPG  12500
#define FILL_BLOCKS 2048       // multiple of 8

// Zero cur, overflow counter, g, cnt.
__global__ void init_kernel(float* __restrict__ ws) {
    int i = blockIdx.x * blockDim.x + threadIdx.x;
    if (i < N_TXN) ((int*)ws)[OFF_CUR + i] = 0;
    if (i < 64) ((int*)ws)[OFF_OVFC + i] = 0;
    if (i < NGRAPH * 64) ws[OFF_G + i] = 0.0f;
    if (i < NGRAPH) ws[OFF_CNT + i] = 0.0f;
}

// Two-stage projection, NUMERICS MATCH REFERENCE STAGING:
//   h = x@Wp + bp  (rounded to f32)   then   z = h@Wh + bh
// (round-3 lesson: folding Wp@Wh reassociates past the bf16-level output
//  tolerance; summation-order changes are fine, stage-elimination is not.)
// Persistent grid-stride; bias-first, k ascending (absmax 0.0 since r5).
#define PB 128
#define PT 512
__global__ __launch_bounds__(PT) void proj2_kernel(
    const float* __restrict__ x, int n_nodes,
    const float* __restrict__ Wp, const float* __restrict__ bp,
    const float* __restrict__ Wh, const float* __restrict__ bh,
    const float* __restrict__ att,      // 64 floats, flattened [H,D]
    float* __restrict__ z_out,          // may be nullptr (tx path)
    float* __restrict__ s_out)          // [n_nodes, 4]
{
    __shared__ float Wp_s[65 * 64];
    __shared__ float Wh_s[64 * 64];
    __shared__ float xh_s[PB * 68];     // x (65 used) then h (64 used)
    __shared__ float bp_s[64], bh_s[64], att_s[64];
    int t = threadIdx.x;

    for (int i = t; i < 65 * 64; i += PT) Wp_s[i] = Wp[i];
    for (int i = t; i < 64 * 64; i += PT) Wh_s[i] = Wh[i];
    if (t < 64) { bp_s[t] = bp[t]; bh_s[t] = bh[t]; att_s[t] = att[t]; }

    int ng = t >> 4;   // 32 node-groups x 4 nodes
    int fg = t & 15;   // float4 feature group
    const float4* Wpf = (const float4*)Wp_s;
    const float4* Whf = (const float4*)Wh_s;

    int ntiles = (n_nodes + PB - 1) / PB;
    for (int tile = blockIdx.x; tile < ntiles; tile += gridDim.x) {
        __syncthreads();    // weights ready / previous tile's xh_s reads done
        int nb = tile * PB;
        int nrem = n_nodes - nb; if (nrem > PB) nrem = PB;
        int tot = nrem * 65;
        for (int i = t; i < tot; i += PT) {
            int n = i / 65, k = i - n * 65;
            xh_s[n * 68 + k] = x[(size_t)nb * 65 + i];
        }
        __syncthreads();

        // stage 1: h = x@Wp + bp
        float4 acc[4];
        float4 b4 = ((const float4*)bp_s)[fg];
        #pragma unroll
        for (int i = 0; i < 4; ++i) acc[i] = b4;
        for (int k = 0; k < 65; ++k) {
            float4 w = Wpf[k * 16 + fg];
            #pragma unroll
            for (int i = 0; i < 4; ++i) {
                float xv = xh_s[(ng * 4 + i) * 68 + k];
                acc[i].x += xv * w.x; acc[i].y += xv * w.y;
                acc[i].z += xv * w.z; acc[i].w += xv * w.w;
            }
        }
        __syncthreads();    // all x reads done before overwrite
        #pragma unroll
        for (int i = 0; i < 4; ++i)
            *(float4*)(&xh_s[(ng * 4 + i) * 68 + fg * 4]) = acc[i];
        __syncthreads();    // h visible to all

        // stage 2: z = h@Wh + bh
        b4 = ((const float4*)bh_s)[fg];
        #pragma unroll
        for (int i = 0; i < 4; ++i) acc[i] = b4;
        for (int k = 0; k < 64; ++k) {
            float4 w = Whf[k * 16 + fg];
            #pragma unroll
            for (int i = 0; i < 4; ++i) {
                float hv = xh_s[(ng * 4 + i) * 68 + k];
                acc[i].x += hv * w.x; acc[i].y += hv * w.y;
                acc[i].z += hv * w.z; acc[i].w += hv * w.w;
            }
        }

        // epilogue: optional z store + per-head att dot
        float a0 = att_s[fg * 4], a1 = att_s[fg * 4 + 1];
        float a2 = att_s[fg * 4 + 2], a3 = att_s[fg * 4 + 3];
        #pragma unroll
        for (int i = 0; i < 4; ++i) {
            int n = ng * 4 + i;
            if (z_out && n < nrem)
                ((float4*)(z_out + (size_t)(nb + n) * 64))[fg] = acc[i];
            float p = acc[i].x * a0 + acc[i].y * a1 + acc[i].z * a2 + acc[i].w * a3;
            p += __shfl_xor(p, 1);
            p += __shfl_xor(p, 2);
            if ((fg & 3) == 0 && n < nrem)
                s_out[(nb + n) * 4 + (fg >> 2)] = p;
        }
    }
}

// Dense fill, dst-range-partitioned (r7 WIN kept). No hist/scan needed:
// slot index comes straight from the atomic counter. Overflow (slot>=DSLOT)
// appended to a global (dst,src) list handled exactly by cleanup_kernel.
__global__ __launch_bounds__(256) void fill_kernel(
    const int* __restrict__ e_src, const int* __restrict__ e_dst,
    int* __restrict__ cur, int* __restrict__ csrd,
    int* __restrict__ ovfc, int2* __restrict__ ovf)
{
    int grp = blockIdx.x & (NGRP - 1);
    int sl  = blockIdx.x >> 3;
    const int NSL = FILL_BLOCKS / NGRP;            // slices per group
    const int per = (NEDGE + NSL - 1) / NSL;       // edges per slice
    int e0 = sl * per;
    int e1 = e0 + per; if (e1 > NEDGE) e1 = NEDGE;
    int lo = grp * DPG, hi = lo + DPG;
    for (int e = e0 + threadIdx.x; e < e1; e += 256) {
        int d = e_dst[e];
        if (d >= lo && d < hi) {
            int p = atomicAdd(&cur[d], 1);
            if (p < DSLOT) csrd[d * DSLOT + p] = e_src[e];
            else {
                int q = atomicAdd(ovfc, 1);
                if (q < OVF_CAP) ovf[q] = make_int2(d, e_src[e]);
            }
        }
    }
}

// Fused edge phase + relu + mean-pool. 16-lane groups, 16 dsts/block.
// Each group computes its dst's feature vector into LDS (zeros for skipped
// deg>DSLOT dsts — cleanup adds those features to g directly — and for
// out-of-range slots). One wave then run-merges rows with equal (sorted)
// batch id and issues ~1-2 atomics per feature per block. txf buffer and
// pool_kernel are gone (25.6 MB traffic + a dispatch).
__global__ __launch_bounds__(256) void gather_kernel(
    const int* __restrict__ csrd, const int* __restrict__ cur,
    const float* __restrict__ s_src, const float* __restrict__ s_dst,
    const float* __restrict__ z, const int* __restrict__ batch,
    float* __restrict__ g, float* __restrict__ cnt)
{
    __shared__ int   se_s[16][16];
    __shared__ float w_s[16][16][4];
    __shared__ float gsum_s[16][68];
    __shared__ int   bid_s[16];
    int grpId = threadIdx.x >> 4;       // 16 groups per block
    int l16 = threadIdx.x & 15;
    int grp = blockIdx.x & (NGRP - 1);
    int li  = (blockIdx.x >> 3) * 16 + grpId;      // [0, 12512)
    bool valid = li < DPG;
    int dst = valid ? grp * DPG + li : 0;
    int deg = valid ? cur[dst] : 0;
    bool skip = deg > DSLOT;            // cleanup owns features; still counted
    if (skip) deg = 0;
    int r0 = dst * DSLOT;
    int h = l16 >> 2;                   // head for this lane's 4 features

    float4 sd = *(const float4*)(s_dst + dst * 4);
    float4 outA = make_float4(0.f, 0.f, 0.f, 0.f);
    float4 outB = make_float4(0.f, 0.f, 0.f, 0.f);
    float4 den = make_float4(0.f, 0.f, 0.f, 0.f);

    if (deg <= 16) {
        // one edge per lane; scores in registers; single pass
        // (deg==0: everything stays 0 and the final write is zeros)
        float4 a4 = make_float4(-1e30f, -1e30f, -1e30f, -1e30f);
        int s = 0;
        if (l16 < deg) {
            s = csrd[r0 + l16];
            float4 ss = *(const float4*)(s_src + s * 4);
            float a;
            a = ss.x + sd.x; a4.x = a >= 0.f ? a : 0.2f * a;
            a = ss.y + sd.y; a4.y = a >= 0.f ? a : 0.2f * a;
            a = ss.z + sd.z; a4.z = a >= 0.f ? a : 0.2f * a;
            a = ss.w + sd.w; a4.w = a >= 0.f ? a : 0.2f * a;
        }
        float4 mx = a4;
        #pragma unroll
        for (int o = 1; o < 16; o <<= 1) {
            mx.x = fmaxf(mx.x, __shfl_xor(mx.x, o));
            mx.y = fmaxf(mx.y, __shfl_xor(mx.y, o));
            mx.z = fmaxf(mx.z, __shfl_xor(mx.z, o));
            mx.w = fmaxf(mx.w, __shfl_xor(mx.w, o));
        }
        float4 w = make_float4(0.f, 0.f, 0.f, 0.f);
        if (l16 < deg) {
            w.x = __expf(a4.x - mx.x);
            w.y = __expf(a4.y - mx.y);
            w.z = __expf(a4.z - mx.z);
            w.w = __expf(a4.w - mx.w);
            den = w;
        }
        se_s[grpId][l16] = s;
        *(float4*)(&w_s[grpId][l16][0]) = w;
        #pragma unroll
        for (int o = 1; o < 16; o <<= 1) {
            den.x += __shfl_xor(den.x, o);
            den.y += __shfl_xor(den.y, o);
            den.z += __shfl_xor(den.z, o);
            den.w += __shfl_xor(den.w, o);
        }
        // feature accumulation, 2-way unrolled (two accumulators)
        int ee = 0;
        for (; ee + 1 < deg; ee += 2) {
            int sa = se_s[grpId][ee];
            int sb = se_s[grpId][ee + 1];
            float wa = w_s[grpId][ee][h];
            float wb = w_s[grpId][ee + 1][h];
            float4 za = *(const float4*)(z + (size_t)sa * 64 + l16 * 4);
            float4 zb = *(const float4*)(z + (size_t)sb * 64 + l16 * 4);
            outA.x += za.x * wa; outA.y += za.y * wa;
            outA.z += za.z * wa; outA.w += za.w * wa;
            outB.x += zb.x * wb; outB.y += zb.y * wb;
            outB.z += zb.z * wb; outB.w += zb.w * wb;
        }
        if (ee < deg) {
            int sa = se_s[grpId][ee];
            float wa = w_s[grpId][ee][h];
            float4 za = *(const float4*)(z + (size_t)sa * 64 + l16 * 4);
            outA.x += za.x * wa; outA.y += za.y * wa;
            outA.z += za.z * wa; outA.w += za.w * wa;
        }
    } else {
        // chunked two-pass (16 < deg <= DSLOT, ~2.6%)
        float4 mx = make_float4(-1e30f, -1e30f, -1e30f, -1e30f);
        for (int base = 0; base < deg; base += 16) {
            if (base + l16 < deg) {
                int s = csrd[r0 + base + l16];
                float4 ss = *(const float4*)(s_src + s * 4);
                float a;
                a = ss.x + sd.x; a = a >= 0.f ? a : 0.2f * a; mx.x = fmaxf(mx.x, a);
                a = ss.y + sd.y; a = a >= 0.f ? a : 0.2f * a; mx.y = fmaxf(mx.y, a);
                a = ss.z + sd.z; a = a >= 0.f ? a : 0.2f * a; mx.z = fmaxf(mx.z, a);
                a = ss.w + sd.w; a = a >= 0.f ? a : 0.2f * a; mx.w = fmaxf(mx.w, a);
            }
        }
        #pragma unroll
        for (int o = 1; o < 16; o <<= 1) {
            mx.x = fmaxf(mx.x, __shfl_xor(mx.x, o));
            mx.y = fmaxf(mx.y, __shfl_xor(mx.y, o));
            mx.z = fmaxf(mx.z, __shfl_xor(mx.z, o));
            mx.w = fmaxf(mx.w, __shfl_xor(mx.w, o));
        }
        for (int base = 0; base < deg; base += 16) {
            int cnt2 = deg - base; if (cnt2 > 16) cnt2 = 16;
            int s = 0;
            float4 w = make_float4(0.f, 0.f, 0.f, 0.f);
            if (l16 < cnt2) {
                s = csrd[r0 + base + l16];
                float4 ss = *(const float4*)(s_src + s * 4);
                float a;
                a = ss.x + sd.x; a = a >= 0.f ? a : 0.2f * a; w.x = __expf(a - mx.x);
                a = ss.y + sd.y; a = a >= 0.f ? a : 0.2f * a; w.y = __expf(a - mx.y);
                a = ss.z + sd.z; a = a >= 0.f ? a : 0.2f * a; w.z = __expf(a - mx.z);
                a = ss.w + sd.w; a = a >= 0.f ? a : 0.2f * a; w.w = __expf(a - mx.w);
                den.x += w.x; den.y += w.y; den.z += w.z; den.w += w.w;
            }
            se_s[grpId][l16] = s;
            *(float4*)(&w_s[grpId][l16][0]) = w;
            for (int ee = 0; ee < cnt2; ++ee) {
                int se = se_s[grpId][ee];
                float wl = w_s[grpId][ee][h];
                float4 zz = *(const float4*)(z + (size_t)se * 64 + l16 * 4);
                outA.x += zz.x * wl; outA.y += zz.y * wl;
                outA.z += zz.z * wl; outA.w += zz.w * wl;
            }
        }
        #pragma unroll
        for (int o = 1; o < 16; o <<= 1) {
            den.x += __shfl_xor(den.x, o);
            den.y += __shfl_xor(den.y, o);
            den.z += __shfl_xor(den.z, o);
            den.w += __shfl_xor(den.w, o);
        }
    }

    float denh = (h == 0) ? den.x : (h == 1) ? den.y : (h == 2) ? den.z : den.w;
    float inv = 1.0f / (denh + 1e-16f);
    float4 r;
    r.x = fmaxf((outA.x + outB.x) * inv, 0.f);
    r.y = fmaxf((outA.y + outB.y) * inv, 0.f);
    r.z = fmaxf((outA.z + outB.z) * inv, 0.f);
    r.w = fmaxf((outA.w + outB.w) * inv, 0.f);
    *(float4*)(&gsum_s[grpId][l16 * 4]) = r;
    if (l16 == 0) bid_s[grpId] = valid ? batch[dst] : -1;
    __syncthreads();

    // pool epilogue: one wave run-merges the 16 rows by (sorted) batch id
    if (threadIdx.x < 64) {
        int f = threadIdx.x;
        float run = 0.f, runc = 0.f;
        int cb = -1;
        for (int i = 0; i < 16; ++i) {
            int b = bid_s[i];
            if (b < 0) continue;
            if (b != cb) {
                if (cb >= 0) {
                    atomicAdd(&g[cb * 64 + f], run);
                    if (f == 0) atomicAdd(&cnt[cb], runc);
                }
                run = 0.f; runc = 0.f; cb = b;
            }
            run += gsum_s[i][f];
            runc += 1.f;
        }
        if (cb >= 0) {
            atomicAdd(&g[cb * 64 + f], run);
            if (f == 0) atomicAdd(&cnt[cb], runc);
        }
    }
}

// Exact handler for deg > DSLOT dsts (expected ~3 nodes; data-driven, exits
// immediately when no overflow). R9 CRASH FIX: inactive groups get deg=0 and
// never touch el[]/global memory; el filled only by active group leaders.
__global__ __launch_bounds__(256) void cleanup_kernel(
    const int* __restrict__ csrd, const int* __restrict__ cur,
    const int* __restrict__ ovfc, const int2* __restrict__ ovf,
    const float* __restrict__ s_src, const float* __restrict__ s_dst,
    const float* __restrict__ z, const int* __restrict__ batch,
    float* __restrict__ g)
{
    int n = ovfc[0];
    if (n <= 0) return;
    if (n > OVF_CAP) n = OVF_CAP;
    __shared__ int od_s[OVF_CAP];
    __shared__ int os_s[OVF_CAP];
    __shared__ int ud_s[256];
    __shared__ int nuniq_s;
    __shared__ int el[16][64];
    int t = threadIdx.x;
    for (int i = t; i < n; i += 256) {
        int2 p = ovf[i]; od_s[i] = p.x; os_s[i] = p.y;
    }
    __syncthreads();
    if (t == 0) {
        int nu = 0;
        for (int i = 0; i < n && nu < 256; ++i) {
            int d = od_s[i]; bool dup = false;
            for (int j = 0; j < nu; ++j) if (ud_s[j] == d) { dup = true; break; }
            if (!dup) ud_s[nu++] = d;
        }
        nuniq_s = nu;
    }
    __syncthreads();
    int nuniq = nuniq_s;
    int g16 = t >> 4, l16 = t & 15, h = l16 >> 2;
    int trips = (nuniq + 15) >> 4;
    for (int tr = 0; tr < trips; ++tr) {
        int u = tr * 16 + g16;
        bool act = u < nuniq;
        int d = act ? ud_s[u] : 0;
        int deg = 0;
        if (act) { deg = cur[d]; if (deg > 64) deg = 64; }
        if (act && l16 == 0) {
            int c2 = 0;
            for (int k = 0; k < DSLOT && c2 < deg; ++k)
                el[g16][c2++] = csrd[d * DSLOT + k];
            for (int i = 0; i < n && c2 < deg; ++i)
                if (od_s[i] == d) el[g16][c2++] = os_s[i];
        }
        __syncthreads();
        float4 sd = *(const float4*)(s_dst + d * 4);
        // pass 1: per-head max over strided edges (deg=0 for inactive: skip)
        float4 mx = make_float4(-1e30f, -1e30f, -1e30f, -1e30f);
        for (int e = l16; e < deg; e += 16) {
            int s = el[g16][e];
            float4 ss = *(const float4*)(s_src + s * 4);
            float a;
            a = ss.x + sd.x; a = a >= 0.f ? a : 0.2f * a; mx.x = fmaxf(mx.x, a);
            a = ss.y + sd.y; a = a >= 0.f ? a : 0.2f * a; mx.y = fmaxf(mx.y, a);
            a = ss.z + sd.z; a = a >= 0.f ? a : 0.2f * a; mx.z = fmaxf(mx.z, a);
            a = ss.w + sd.w; a = a >= 0.f ? a : 0.2f * a; mx.w = fmaxf(mx.w, a);
        }
        #pragma unroll
        for (int o = 1; o < 16; o <<= 1) {
            mx.x = fmaxf(mx.x, __shfl_xor(mx.x, o));
            mx.y = fmaxf(mx.y, __shfl_xor(mx.y, o));
            mx.z = fmaxf(mx.z, __shfl_xor(mx.z, o));
            mx.w = fmaxf(mx.w, __shfl_xor(mx.w, o));
        }
        // pass 2: denominator over strided edges
        float4 den = make_float4(0.f, 0.f, 0.f, 0.f);
        for (int e = l16; e < deg; e += 16) {
            int s = el[g16][e];
            float4 ss = *(const float4*)(s_src + s * 4);
            float a;
            a = ss.x + sd.x; a = a >= 0.f ? a : 0.2f * a; den.x += __expf(a - mx.x);
            a = ss.y + sd.y; a = a >= 0.f ? a : 0.2f * a; den.y += __expf(a - mx.y);
            a = ss.z + sd.z; a = a >= 0.f ? a : 0.2f * a; den.z += __expf(a - mx.z);
            a = ss.w + sd.w; a = a >= 0.f ? a : 0.2f * a; den.w += __expf(a - mx.w);
        }
        #pragma unroll
        for (int o = 1; o < 16; o <<= 1) {
            den.x += __shfl_xor(den.x, o);
            den.y += __shfl_xor(den.y, o);
            den.z += __shfl_xor(den.z, o);
            den.w += __shfl_xor(den.w, o);
        }
        // pass 3: each lane recomputes per-edge weight for its own head
        float mh  = (h == 0) ? mx.x : (h == 1) ? mx.y : (h == 2) ? mx.z : mx.w;
        float sdh = (h == 0) ? sd.x : (h == 1) ? sd.y : (h == 2) ? sd.z : sd.w;
        float4 out = make_float4(0.f, 0.f, 0.f, 0.f);
        for (int ee = 0; ee < deg; ++ee) {
            int s = el[g16][ee];
            float a = s_src[s * 4 + h] + sdh;
            a = a >= 0.f ? a : 0.2f * a;
            float w = __expf(a - mh);
            float4 zz = *(const float4*)(z + (size_t)s * 64 + l16 * 4);
            out.x += zz.x * w; out.y += zz.y * w;
            out.z += zz.z * w; out.w += zz.w * w;
        }
        if (act) {
            float denh = (h == 0) ? den.x : (h == 1) ? den.y : (h == 2) ? den.z : den.w;
            float inv = 1.0f / (denh + 1e-16f);
            int b = batch[d];
            float* gp = g + b * 64 + l16 * 4;
            atomicAdd(gp + 0, fmaxf(out.x * inv, 0.f));
            atomicAdd(gp + 1, fmaxf(out.y * inv, 0.f));
            atomicAdd(gp + 2, fmaxf(out.z * inv, 0.f));
            atomicAdd(gp + 3, fmaxf(out.w * inv, 0.f));
        }
        __syncthreads();
    }
}

// Classifier: out = relu(gmean @ W1 + b1) @ W2 + b2. One block, 128 threads.
__global__ __launch_bounds__(128) void classifier_kernel(
    const float* __restrict__ g, const float* __restrict__ cnt,
    const float* __restrict__ W1, const float* __restrict__ b1,
    const float* __restrict__ W2, const float* __restrict__ b2,
    float* __restrict__ out)
{
    __shared__ float W1s[64 * 32];
    __shared__ float W2s[32];
    int t = threadIdx.x;
    for (int i = t; i < 64 * 32; i += 128) W1s[i] = W1[i];
    if (t < 32) W2s[t] = W2[t];
    __syncthreads();
    if (t >= NGRAPH) return;

    float c = fmaxf(cnt[t], 1.0f);
    float gm[64];
    #pragma unroll
    for (int k = 0; k < 64; ++k) gm[k] = g[t * 64 + k] / c;

    float o = b2[0];
    for (int j = 0; j < 32; ++j) {
        float acc = b1[j];
        #pragma unroll
        for (int k = 0; k < 64; ++k) acc += gm[k] * W1s[k * 32 + j];
        o += fmaxf(acc, 0.f) * W2s[j];
    }
    out[t] = o;
}

extern "C" void kernel_launch(void* const* d_in, const int* in_sizes, int n_in,
                              void* d_out, int out_size, void* d_ws, size_t ws_size,
                              hipStream_t stream)
{
    (void)in_sizes; (void)n_in; (void)out_size; (void)ws_size;

    const float* x_tx      = (const float*)d_in[0];
    const float* x_addr    = (const float*)d_in[1];
    const float* Wp_tx     = (const float*)d_in[2];
    const float* bp_tx     = (const float*)d_in[3];
    const float* Wp_ad     = (const float*)d_in[4];
    const float* bp_ad     = (const float*)d_in[5];
    const float* Wh_tx     = (const float*)d_in[6];
    const float* bh_tx     = (const float*)d_in[7];
    const float* Wh_ad     = (const float*)d_in[8];
    const float* bh_ad     = (const float*)d_in[9];
    // d_in[10],[11]: att_*_ta — dead (out_addr discarded by the reference)
    const float* att_src_at = (const float*)d_in[12];
    const float* att_dst_at = (const float*)d_in[13];
    // d_in[14..16]: W_k,b_k,q — dead (softmax over 1 metapath == identity)
    const float* W_c1      = (const float*)d_in[17];
    const float* b_c1      = (const float*)d_in[18];
    const float* W_c2      = (const float*)d_in[19];
    const float* b_c2      = (const float*)d_in[20];
    // d_in[21]: edge_ta — dead
    const int*   edge_at   = (const int*)d_in[22];   // [2, E] row-major
    const int*   batch_tx  = (const int*)d_in[23];

    float* ws    = (float*)d_ws;
    float* z_ad  = ws + OFF_Z;
    float* s_src = ws + OFF_SS;
    float* s_dst = ws + OFF_SD;
    int*   csrd  = (int*)ws + OFF_CSRD;
    int*   cur   = (int*)ws + OFF_CUR;
    int*   ovfc  = (int*)ws + OFF_OVFC;
    int2*  ovf   = (int2*)((int*)ws + OFF_OVF);
    float* g     = ws + OFF_G;
    float* cnt   = ws + OFF_CNT;

    const int* e_src = edge_at;          // addr ids (source)
    const int* e_dst = edge_at + NEDGE;  // tx ids (destination)

    init_kernel<<<(N_TXN + 255) / 256, 256, 0, stream>>>(ws);

    proj2_kernel<<<512, PT, 0, stream>>>(
        x_addr, N_ADDRN, Wp_ad, bp_ad, Wh_ad, bh_ad, att_src_at, z_ad, s_src);
    proj2_kernel<<<512, PT, 0, stream>>>(
        x_tx, N_TXN, Wp_tx, bp_tx, Wh_tx, bh_tx, att_dst_at, nullptr, s_dst);

    fill_kernel<<<FILL_BLOCKS, 256, 0, stream>>>(
        e_src, e_dst, cur, csrd, ovfc, ovf);

    // grid: 8 groups x 782 blocks x 16 dst-groups = 100096 slots (li guard)
    gather_kernel<<<8 * 782, 256, 0, stream>>>(
        csrd, cur, s_src, s_dst, z_ad, batch_tx, g, cnt);

    cleanup_kernel<<<1, 256, 0, stream>>>(
        csrd, cur, ovfc, ovf, s_src, s_dst, z_ad, batch_tx, g);

    classifier_kernel<<<1, 128, 0, stream>>>(
        g, cnt, W_c1, b_c1, W_c2, b_c2, (float*)d_out);
}

// Round 11
// 314.908 us; speedup vs baseline: 5.2889x; 1.0550x over previous
//
#include <hip/hip_runtime.h>

// Problem constants (fixed by the reference)
#define N_TXN   100000
#define N_ADDRN 100000
#define NEDGE   1000000
#define NGRAPH  128

// Dense-slot CSR: 24 slots/dst (P[Poisson(10) > 24] ~ 3e-5 -> overflow list)
#define DSLOT   24
#define OVF_CAP 2048

// Workspace layout in 4-byte units (38.9 MB, under the 59.3 MB proven bound)
#define OFF_Z     0            // [N_ADDR*64] f32  z_addr features
#define OFF_SS    6400000      // [N_ADDR*4] f32  (z_addr . att_src_at)
#define OFF_SD    6800000      // [N_TX*4]   f32  (z_tx . att_dst_at)
#define OFF_CSRD  7200000      // [N_TX*24]  int  dense src slots
#define OFF_CUR   9600000      // [N_TX]     int  per-dst edge count
#define OFF_OVFC  9700000      // [64]       int  overflow counter
#define OFF_OVF   9700064      // [2*OVF_CAP]int  overflow (dst,src) pairs
#define OFF_G     9704160      // [128*64]   f32  pooled graph sums
#define OFF_CNT   9712352      // [128]      f32  counts per graph

// dst-range partitioning (fill/gather XCD-locality): 8 groups x 12500 dsts
#define NGRP 8
#define DPG  12500

#define PB 128
#define PT 512
#define NPROJB 512             // role-blocks per projection
#define NFILLB 1024            // fill role-blocks (8 groups x 128 slices)

// Zero cur, overflow counter, g, cnt.
__global__ void init_kernel(float* __restrict__ ws) {
    int i = blockIdx.x * blockDim.x + threadIdx.x;
    if (i < N_TXN) ((int*)ws)[OFF_CUR + i] = 0;
    if (i < 64) ((int*)ws)[OFF_OVFC + i] = 0;
    if (i < NGRAPH * 64) ws[OFF_G + i] = 0.0f;
    if (i < NGRAPH) ws[OFF_CNT + i] = 0.0f;
}

// Two-stage projection body, NUMERICS MATCH REFERENCE STAGING (r3 lesson):
//   h = x@Wp + bp (rounded to f32) then z = h@Wh + bh; bias-first, k asc —
//   bit-identical to r10's proj2 (absmax 0.0 since r5).
__device__ __forceinline__ void proj_role(
    const float* __restrict__ x, int n_nodes,
    const float* __restrict__ Wp, const float* __restrict__ bp,
    const float* __restrict__ Wh, const float* __restrict__ bh,
    const float* __restrict__ att,
    float* __restrict__ z_out, float* __restrict__ s_out,
    int rb,
    float* Wp_s, float* Wh_s, float* xh_s,
    float* bp_s, float* bh_s, float* att_s)
{
    int t = threadIdx.x;
    for (int i = t; i < 65 * 64; i += PT) Wp_s[i] = Wp[i];
    for (int i = t; i < 64 * 64; i += PT) Wh_s[i] = Wh[i];
    if (t < 64) { bp_s[t] = bp[t]; bh_s[t] = bh[t]; att_s[t] = att[t]; }

    int ng = t >> 4;   // 32 node-groups x 4 nodes
    int fg = t & 15;   // float4 feature group
    const float4* Wpf = (const float4*)Wp_s;
    const float4* Whf = (const float4*)Wh_s;

    int ntiles = (n_nodes + PB - 1) / PB;
    for (int tile = rb; tile < ntiles; tile += NPROJB) {
        __syncthreads();    // weights ready / previous tile's xh_s reads done
        int nb = tile * PB;
        int nrem = n_nodes - nb; if (nrem > PB) nrem = PB;
        int tot = nrem * 65;
        for (int i = t; i < tot; i += PT) {
            int n = i / 65, k = i - n * 65;
            xh_s[n * 68 + k] = x[(size_t)nb * 65 + i];
        }
        __syncthreads();

        // stage 1: h = x@Wp + bp
        float4 acc[4];
        float4 b4 = ((const float4*)bp_s)[fg];
        #pragma unroll
        for (int i = 0; i < 4; ++i) acc[i] = b4;
        for (int k = 0; k < 65; ++k) {
            float4 w = Wpf[k * 16 + fg];
            #pragma unroll
            for (int i = 0; i < 4; ++i) {
                float xv = xh_s[(ng * 4 + i) * 68 + k];
                acc[i].x += xv * w.x; acc[i].y += xv * w.y;
                acc[i].z += xv * w.z; acc[i].w += xv * w.w;
            }
        }
        __syncthreads();    // all x reads done before overwrite
        #pragma unroll
        for (int i = 0; i < 4; ++i)
            *(float4*)(&xh_s[(ng * 4 + i) * 68 + fg * 4]) = acc[i];
        __syncthreads();    // h visible to all

        // stage 2: z = h@Wh + bh
        b4 = ((const float4*)bh_s)[fg];
        #pragma unroll
        for (int i = 0; i < 4; ++i) acc[i] = b4;
        for (int k = 0; k < 64; ++k) {
            float4 w = Whf[k * 16 + fg];
            #pragma unroll
            for (int i = 0; i < 4; ++i) {
                float hv = xh_s[(ng * 4 + i) * 68 + k];
                acc[i].x += hv * w.x; acc[i].y += hv * w.y;
                acc[i].z += hv * w.z; acc[i].w += hv * w.w;
            }
        }

        // epilogue: optional z store + per-head att dot
        float a0 = att_s[fg * 4], a1 = att_s[fg * 4 + 1];
        float a2 = att_s[fg * 4 + 2], a3 = att_s[fg * 4 + 3];
        #pragma unroll
        for (int i = 0; i < 4; ++i) {
            int n = ng * 4 + i;
            if (z_out && n < nrem)
                ((float4*)(z_out + (size_t)(nb + n) * 64))[fg] = acc[i];
            float p = acc[i].x * a0 + acc[i].y * a1 + acc[i].z * a2 + acc[i].w * a3;
            p += __shfl_xor(p, 1);
            p += __shfl_xor(p, 2);
            if ((fg & 3) == 0 && n < nrem)
                s_out[(nb + n) * 4 + (fg >> 2)] = p;
        }
    }
}

// Fill role body: dense dst-partitioned scatter (r7 WRITE_SIZE fix + r9/r10
// dense slots). fb in [0, NFILLB): grp = fb&7 owns dsts [grp*DPG,(grp+1)*DPG)
// and slice fb>>3 of the edge list.
__device__ __forceinline__ void fill_role(
    const int* __restrict__ e_src, const int* __restrict__ e_dst,
    int* __restrict__ cur, int* __restrict__ csrd,
    int* __restrict__ ovfc, int2* __restrict__ ovf, int fb)
{
    int grp = fb & (NGRP - 1);
    int sl  = fb >> 3;
    const int NSL = NFILLB / NGRP;                 // 128 slices per group
    const int per = (NEDGE + NSL - 1) / NSL;       // edges per slice
    int e0 = sl * per;
    int e1 = e0 + per; if (e1 > NEDGE) e1 = NEDGE;
    int lo = grp * DPG, hi = lo + DPG;
    for (int e = e0 + threadIdx.x; e < e1; e += PT) {
        int d = e_dst[e];
        if (d >= lo && d < hi) {
            int p = atomicAdd(&cur[d], 1);
            if (p < DSLOT) csrd[d * DSLOT + p] = e_src[e];
            else {
                int q = atomicAdd(ovfc, 1);
                if (q < OVF_CAP) ovf[q] = make_int2(d, e_src[e]);
            }
        }
    }
}

// ROLE-FUSED mega-kernel: proj_addr / proj_tx / fill in one dispatch.
// r10 diagnosis: these three have NO mutual dependencies but were serialized
// as separate dispatches (~250us of the 332 total outside gather). Role by
// blockIdx&3 interleaves VALU-bound proj blocks with latency/atomic-bound
// fill blocks on the same CUs (complementary pipes).
__global__ __launch_bounds__(PT) void fused_kernel(
    const float* __restrict__ x_ad,
    const float* __restrict__ Wp_ad, const float* __restrict__ bp_ad,
    const float* __restrict__ Wh_ad, const float* __restrict__ bh_ad,
    const float* __restrict__ att_src,
    const float* __restrict__ x_tx,
    const float* __restrict__ Wp_tx, const float* __restrict__ bp_tx,
    const float* __restrict__ Wh_tx, const float* __restrict__ bh_tx,
    const float* __restrict__ att_dst,
    float* __restrict__ z_ad, float* __restrict__ s_src,
    float* __restrict__ s_dst,
    const int* __restrict__ e_src, const int* __restrict__ e_dst,
    int* __restrict__ cur, int* __restrict__ csrd,
    int* __restrict__ ovfc, int2* __restrict__ ovf)
{
    __shared__ float Wp_s[65 * 64];
    __shared__ float Wh_s[64 * 64];
    __shared__ float xh_s[PB * 68];
    __shared__ float bp_s[64], bh_s[64], att_s[64];

    int role = blockIdx.x & 3;
    int rb   = blockIdx.x >> 2;        // role-block index, 0..511
    if (role == 0) {
        proj_role(x_ad, N_ADDRN, Wp_ad, bp_ad, Wh_ad, bh_ad, att_src,
                  z_ad, s_src, rb, Wp_s, Wh_s, xh_s, bp_s, bh_s, att_s);
    } else if (role == 1) {
        proj_role(x_tx, N_TXN, Wp_tx, bp_tx, Wh_tx, bh_tx, att_dst,
                  nullptr, s_dst, rb, Wp_s, Wh_s, xh_s, bp_s, bh_s, att_s);
    } else {
        fill_role(e_src, e_dst, cur, csrd, ovfc, ovf,
                  (role - 2) * NPROJB + rb);
    }
}

// Fused edge phase + relu + mean-pool (r10 WIN kept), 16-lane groups.
// r11: 4-way unrolled feature loop (4 outstanding z loads, was 2).
__global__ __launch_bounds__(256) void gather_kernel(
    const int* __restrict__ csrd, const int* __restrict__ cur,
    const float* __restrict__ s_src, const float* __restrict__ s_dst,
    const float* __restrict__ z, const int* __restrict__ batch,
    float* __restrict__ g, float* __restrict__ cnt)
{
    __shared__ int   se_s[16][16];
    __shared__ float w_s[16][16][4];
    __shared__ float gsum_s[16][68];
    __shared__ int   bid_s[16];
    int grpId = threadIdx.x >> 4;       // 16 groups per block
    int l16 = threadIdx.x & 15;
    int grp = blockIdx.x & (NGRP - 1);
    int li  = (blockIdx.x >> 3) * 16 + grpId;      // [0, 12512)
    bool valid = li < DPG;
    int dst = valid ? grp * DPG + li : 0;
    int deg = valid ? cur[dst] : 0;
    bool skip = deg > DSLOT;            // cleanup owns features; still counted
    if (skip) deg = 0;
    int r0 = dst * DSLOT;
    int h = l16 >> 2;                   // head for this lane's 4 features

    float4 sd = *(const float4*)(s_dst + dst * 4);
    float4 outA = make_float4(0.f, 0.f, 0.f, 0.f);
    float4 outB = make_float4(0.f, 0.f, 0.f, 0.f);
    float4 outC = make_float4(0.f, 0.f, 0.f, 0.f);
    float4 outD = make_float4(0.f, 0.f, 0.f, 0.f);
    float4 den = make_float4(0.f, 0.f, 0.f, 0.f);

    if (deg <= 16) {
        // one edge per lane; scores in registers; single pass
        float4 a4 = make_float4(-1e30f, -1e30f, -1e30f, -1e30f);
        int s = 0;
        if (l16 < deg) {
            s = csrd[r0 + l16];
            float4 ss = *(const float4*)(s_src + s * 4);
            float a;
            a = ss.x + sd.x; a4.x = a >= 0.f ? a : 0.2f * a;
            a = ss.y + sd.y; a4.y = a >= 0.f ? a : 0.2f * a;
            a = ss.z + sd.z; a4.z = a >= 0.f ? a : 0.2f * a;
            a = ss.w + sd.w; a4.w = a >= 0.f ? a : 0.2f * a;
        }
        float4 mx = a4;
        #pragma unroll
        for (int o = 1; o < 16; o <<= 1) {
            mx.x = fmaxf(mx.x, __shfl_xor(mx.x, o));
            mx.y = fmaxf(mx.y, __shfl_xor(mx.y, o));
            mx.z = fmaxf(mx.z, __shfl_xor(mx.z, o));
            mx.w = fmaxf(mx.w, __shfl_xor(mx.w, o));
        }
        float4 w = make_float4(0.f, 0.f, 0.f, 0.f);
        if (l16 < deg) {
            w.x = __expf(a4.x - mx.x);
            w.y = __expf(a4.y - mx.y);
            w.z = __expf(a4.z - mx.z);
            w.w = __expf(a4.w - mx.w);
            den = w;
        }
        se_s[grpId][l16] = s;
        *(float4*)(&w_s[grpId][l16][0]) = w;
        #pragma unroll
        for (int o = 1; o < 16; o <<= 1) {
            den.x += __shfl_xor(den.x, o);
            den.y += __shfl_xor(den.y, o);
            den.z += __shfl_xor(den.z, o);
            den.w += __shfl_xor(den.w, o);
        }
        // feature accumulation, 4-way unrolled (4 outstanding loads)
        int ee = 0;
        for (; ee + 3 < deg; ee += 4) {
            int sa = se_s[grpId][ee],     sb = se_s[grpId][ee + 1];
            int sc = se_s[grpId][ee + 2], sdd = se_s[grpId][ee + 3];
            float wa = w_s[grpId][ee][h],     wb = w_s[grpId][ee + 1][h];
            float wc = w_s[grpId][ee + 2][h], wd = w_s[grpId][ee + 3][h];
            float4 za = *(const float4*)(z + (size_t)sa * 64 + l16 * 4);
            float4 zb = *(const float4*)(z + (size_t)sb * 64 + l16 * 4);
            float4 zc = *(const float4*)(z + (size_t)sc * 64 + l16 * 4);
            float4 zd = *(const float4*)(z + (size_t)sdd * 64 + l16 * 4);
            outA.x += za.x * wa; outA.y += za.y * wa;
            outA.z += za.z * wa; outA.w += za.w * wa;
            outB.x += zb.x * wb; outB.y += zb.y * wb;
            outB.z += zb.z * wb; outB.w += zb.w * wb;
            outC.x += zc.x * wc; outC.y += zc.y * wc;
            outC.z += zc.z * wc; outC.w += zc.w * wc;
            outD.x += zd.x * wd; outD.y += zd.y * wd;
            outD.z += zd.z * wd; outD.w += zd.w * wd;
        }
        for (; ee < deg; ++ee) {
            int sa = se_s[grpId][ee];
            float wa = w_s[grpId][ee][h];
            float4 za = *(const float4*)(z + (size_t)sa * 64 + l16 * 4);
            outA.x += za.x * wa; outA.y += za.y * wa;
            outA.z += za.z * wa; outA.w += za.w * wa;
        }
    } else {
        // chunked two-pass (16 < deg <= DSLOT, ~2.6%)
        float4 mx = make_float4(-1e30f, -1e30f, -1e30f, -1e30f);
        for (int base = 0; base < deg; base += 16) {
            if (base + l16 < deg) {
                int s = csrd[r0 + base + l16];
                float4 ss = *(const float4*)(s_src + s * 4);
                float a;
                a = ss.x + sd.x; a = a >= 0.f ? a : 0.2f * a; mx.x = fmaxf(mx.x, a);
                a = ss.y + sd.y; a = a >= 0.f ? a : 0.2f * a; mx.y = fmaxf(mx.y, a);
                a = ss.z + sd.z; a = a >= 0.f ? a : 0.2f * a; mx.z = fmaxf(mx.z, a);
                a = ss.w + sd.w; a = a >= 0.f ? a : 0.2f * a; mx.w = fmaxf(mx.w, a);
            }
        }
        #pragma unroll
        for (int o = 1; o < 16; o <<= 1) {
            mx.x = fmaxf(mx.x, __shfl_xor(mx.x, o));
            mx.y = fmaxf(mx.y, __shfl_xor(mx.y, o));
            mx.z = fmaxf(mx.z, __shfl_xor(mx.z, o));
            mx.w = fmaxf(mx.w, __shfl_xor(mx.w, o));
        }
        for (int base = 0; base < deg; base += 16) {
            int cnt2 = deg - base; if (cnt2 > 16) cnt2 = 16;
            int s = 0;
            float4 w = make_float4(0.f, 0.f, 0.f, 0.f);
            if (l16 < cnt2) {
                s = csrd[r0 + base + l16];
                float4 ss = *(const float4*)(s_src + s * 4);
                float a;
                a = ss.x + sd.x; a = a >= 0.f ? a : 0.2f * a; w.x = __expf(a - mx.x);
                a = ss.y + sd.y; a = a >= 0.f ? a : 0.2f * a; w.y = __expf(a - mx.y);
                a = ss.z + sd.z; a = a >= 0.f ? a : 0.2f * a; w.z = __expf(a - mx.z);
                a = ss.w + sd.w; a = a >= 0.f ? a : 0.2f * a; w.w = __expf(a - mx.w);
                den.x += w.x; den.y += w.y; den.z += w.z; den.w += w.w;
            }
            se_s[grpId][l16] = s;
            *(float4*)(&w_s[grpId][l16][0]) = w;
            for (int ee = 0; ee < cnt2; ++ee) {
                int se = se_s[grpId][ee];
                float wl = w_s[grpId][ee][h];
                float4 zz = *(const float4*)(z + (size_t)se * 64 + l16 * 4);
                outA.x += zz.x * wl; outA.y += zz.y * wl;
                outA.z += zz.z * wl; outA.w += zz.w * wl;
            }
        }
        #pragma unroll
        for (int o = 1; o < 16; o <<= 1) {
            den.x += __shfl_xor(den.x, o);
            den.y += __shfl_xor(den.y, o);
            den.z += __shfl_xor(den.z, o);
            den.w += __shfl_xor(den.w, o);
        }
    }

    float denh = (h == 0) ? den.x : (h == 1) ? den.y : (h == 2) ? den.z : den.w;
    float inv = 1.0f / (denh + 1e-16f);
    float4 r;
    r.x = fmaxf((outA.x + outB.x + outC.x + outD.x) * inv, 0.f);
    r.y = fmaxf((outA.y + outB.y + outC.y + outD.y) * inv, 0.f);
    r.z = fmaxf((outA.z + outB.z + outC.z + outD.z) * inv, 0.f);
    r.w = fmaxf((outA.w + outB.w + outC.w + outD.w) * inv, 0.f);
    *(float4*)(&gsum_s[grpId][l16 * 4]) = r;
    if (l16 == 0) bid_s[grpId] = valid ? batch[dst] : -1;
    __syncthreads();

    // pool epilogue: one wave run-merges the 16 rows by (sorted) batch id
    if (threadIdx.x < 64) {
        int f = threadIdx.x;
        float run = 0.f, runc = 0.f;
        int cb = -1;
        for (int i = 0; i < 16; ++i) {
            int b = bid_s[i];
            if (b < 0) continue;
            if (b != cb) {
                if (cb >= 0) {
                    atomicAdd(&g[cb * 64 + f], run);
                    if (f == 0) atomicAdd(&cnt[cb], runc);
                }
                run = 0.f; runc = 0.f; cb = b;
            }
            run += gsum_s[i][f];
            runc += 1.f;
        }
        if (cb >= 0) {
            atomicAdd(&g[cb * 64 + f], run);
            if (f == 0) atomicAdd(&cnt[cb], runc);
        }
    }
}

// Exact handler for deg > DSLOT dsts (expected ~3 nodes; data-driven, exits
// immediately when no overflow). Inactive groups get deg=0 (r10 fix held).
__global__ __launch_bounds__(256) void cleanup_kernel(
    const int* __restrict__ csrd, const int* __restrict__ cur,
    const int* __restrict__ ovfc, const int2* __restrict__ ovf,
    const float* __restrict__ s_src, const float* __restrict__ s_dst,
    const float* __restrict__ z, const int* __restrict__ batch,
    float* __restrict__ g)
{
    int n = ovfc[0];
    if (n <= 0) return;
    if (n > OVF_CAP) n = OVF_CAP;
    __shared__ int od_s[OVF_CAP];
    __shared__ int os_s[OVF_CAP];
    __shared__ int ud_s[256];
    __shared__ int nuniq_s;
    __shared__ int el[16][64];
    int t = threadIdx.x;
    for (int i = t; i < n; i += 256) {
        int2 p = ovf[i]; od_s[i] = p.x; os_s[i] = p.y;
    }
    __syncthreads();
    if (t == 0) {
        int nu = 0;
        for (int i = 0; i < n && nu < 256; ++i) {
            int d = od_s[i]; bool dup = false;
            for (int j = 0; j < nu; ++j) if (ud_s[j] == d) { dup = true; break; }
            if (!dup) ud_s[nu++] = d;
        }
        nuniq_s = nu;
    }
    __syncthreads();
    int nuniq = nuniq_s;
    int g16 = t >> 4, l16 = t & 15, h = l16 >> 2;
    int trips = (nuniq + 15) >> 4;
    for (int tr = 0; tr < trips; ++tr) {
        int u = tr * 16 + g16;
        bool act = u < nuniq;
        int d = act ? ud_s[u] : 0;
        int deg = 0;
        if (act) { deg = cur[d]; if (deg > 64) deg = 64; }
        if (act && l16 == 0) {
            int c2 = 0;
            for (int k = 0; k < DSLOT && c2 < deg; ++k)
                el[g16][c2++] = csrd[d * DSLOT + k];
            for (int i = 0; i < n && c2 < deg; ++i)
                if (od_s[i] == d) el[g16][c2++] = os_s[i];
        }
        __syncthreads();
        float4 sd = *(const float4*)(s_dst + d * 4);
        float4 mx = make_float4(-1e30f, -1e30f, -1e30f, -1e30f);
        for (int e = l16; e < deg; e += 16) {
            int s = el[g16][e];
            float4 ss = *(const float4*)(s_src + s * 4);
            float a;
            a = ss.x + sd.x; a = a >= 0.f ? a : 0.2f * a; mx.x = fmaxf(mx.x, a);
            a = ss.y + sd.y; a = a >= 0.f ? a : 0.2f * a; mx.y = fmaxf(mx.y, a);
            a = ss.z + sd.z; a = a >= 0.f ? a : 0.2f * a; mx.z = fmaxf(mx.z, a);
            a = ss.w + sd.w; a = a >= 0.f ? a : 0.2f * a; mx.w = fmaxf(mx.w, a);
        }
        #pragma unroll
        for (int o = 1; o < 16; o <<= 1) {
            mx.x = fmaxf(mx.x, __shfl_xor(mx.x, o));
            mx.y = fmaxf(mx.y, __shfl_xor(mx.y, o));
            mx.z = fmaxf(mx.z, __shfl_xor(mx.z, o));
            mx.w = fmaxf(mx.w, __shfl_xor(mx.w, o));
        }
        float4 den = make_float4(0.f, 0.f, 0.f, 0.f);
        for (int e = l16; e < deg; e += 16) {
            int s = el[g16][e];
            float4 ss = *(const float4*)(s_src + s * 4);
            float a;
            a = ss.x + sd.x; a = a >= 0.f ? a : 0.2f * a; den.x += __expf(a - mx.x);
            a = ss.y + sd.y; a = a >= 0.f ? a : 0.2f * a; den.y += __expf(a - mx.y);
            a = ss.z + sd.z; a = a >= 0.f ? a : 0.2f * a; den.z += __expf(a - mx.z);
            a = ss.w + sd.w; a = a >= 0.f ? a : 0.2f * a; den.w += __expf(a - mx.w);
        }
        #pragma unroll
        for (int o = 1; o < 16; o <<= 1) {
            den.x += __shfl_xor(den.x, o);
            den.y += __shfl_xor(den.y, o);
            den.z += __shfl_xor(den.z, o);
            den.w += __shfl_xor(den.w, o);
        }
        float mh  = (h == 0) ? mx.x : (h == 1) ? mx.y : (h == 2) ? mx.z : mx.w;
        float sdh = (h == 0) ? sd.x : (h == 1) ? sd.y : (h == 2) ? sd.z : sd.w;
        float4 out = make_float4(0.f, 0.f, 0.f, 0.f);
        for (int ee = 0; ee < deg; ++ee) {
            int s = el[g16][ee];
            float a = s_src[s * 4 + h] + sdh;
            a = a >= 0.f ? a : 0.2f * a;
            float w = __expf(a - mh);
            float4 zz = *(const float4*)(z + (size_t)s * 64 + l16 * 4);
            out.x += zz.x * w; out.y += zz.y * w;
            out.z += zz.z * w; out.w += zz.w * w;
        }
        if (act) {
            float denh = (h == 0) ? den.x : (h == 1) ? den.y : (h == 2) ? den.z : den.w;
            float inv = 1.0f / (denh + 1e-16f);
            int b = batch[d];
            float* gp = g + b * 64 + l16 * 4;
            atomicAdd(gp + 0, fmaxf(out.x * inv, 0.f));
            atomicAdd(gp + 1, fmaxf(out.y * inv, 0.f));
            atomicAdd(gp + 2, fmaxf(out.z * inv, 0.f));
            atomicAdd(gp + 3, fmaxf(out.w * inv, 0.f));
        }
        __syncthreads();
    }
}

// Classifier: out = relu(gmean @ W1 + b1) @ W2 + b2. One block, 128 threads.
__global__ __launch_bounds__(128) void classifier_kernel(
    const float* __restrict__ g, const float* __restrict__ cnt,
    const float* __restrict__ W1, const float* __restrict__ b1,
    const float* __restrict__ W2, const float* __restrict__ b2,
    float* __restrict__ out)
{
    __shared__ float W1s[64 * 32];
    __shared__ float W2s[32];
    int t = threadIdx.x;
    for (int i = t; i < 64 * 32; i += 128) W1s[i] = W1[i];
    if (t < 32) W2s[t] = W2[t];
    __syncthreads();
    if (t >= NGRAPH) return;

    float c = fmaxf(cnt[t], 1.0f);
    float gm[64];
    #pragma unroll
    for (int k = 0; k < 64; ++k) gm[k] = g[t * 64 + k] / c;

    float o = b2[0];
    for (int j = 0; j < 32; ++j) {
        float acc = b1[j];
        #pragma unroll
        for (int k = 0; k < 64; ++k) acc += gm[k] * W1s[k * 32 + j];
        o += fmaxf(acc, 0.f) * W2s[j];
    }
    out[t] = o;
}

extern "C" void kernel_launch(void* const* d_in, const int* in_sizes, int n_in,
                              void* d_out, int out_size, void* d_ws, size_t ws_size,
                              hipStream_t stream)
{
    (void)in_sizes; (void)n_in; (void)out_size; (void)ws_size;

    const float* x_tx      = (const float*)d_in[0];
    const float* x_addr    = (const float*)d_in[1];
    const float* Wp_tx     = (const float*)d_in[2];
    const float* bp_tx     = (const float*)d_in[3];
    const float* Wp_ad     = (const float*)d_in[4];
    const float* bp_ad     = (const float*)d_in[5];
    const float* Wh_tx     = (const float*)d_in[6];
    const float* bh_tx     = (const float*)d_in[7];
    const float* Wh_ad     = (const float*)d_in[8];
    const float* bh_ad     = (const float*)d_in[9];
    // d_in[10],[11]: att_*_ta — dead (out_addr discarded by the reference)
    const float* att_src_at = (const float*)d_in[12];
    const float* att_dst_at = (const float*)d_in[13];
    // d_in[14..16]: W_k,b_k,q — dead (softmax over 1 metapath == identity)
    const float* W_c1      = (const float*)d_in[17];
    const float* b_c1      = (const float*)d_in[18];
    const float* W_c2      = (const float*)d_in[19];
    const float* b_c2      = (const float*)d_in[20];
    // d_in[21]: edge_ta — dead
    const int*   edge_at   = (const int*)d_in[22];   // [2, E] row-major
    const int*   batch_tx  = (const int*)d_in[23];

    float* ws    = (float*)d_ws;
    float* z_ad  = ws + OFF_Z;
    float* s_src = ws + OFF_SS;
    float* s_dst = ws + OFF_SD;
    int*   csrd  = (int*)ws + OFF_CSRD;
    int*   cur   = (int*)ws + OFF_CUR;
    int*   ovfc  = (int*)ws + OFF_OVFC;
    int2*  ovf   = (int2*)((int*)ws + OFF_OVF);
    float* g     = ws + OFF_G;
    float* cnt   = ws + OFF_CNT;

    const int* e_src = edge_at;          // addr ids (source)
    const int* e_dst = edge_at + NEDGE;  // tx ids (destination)

    init_kernel<<<(N_TXN + 255) / 256, 256, 0, stream>>>(ws);

    // 2048 blocks: role = blockIdx&3 (0=proj_addr, 1=proj_tx, 2-3=fill)
    fused_kernel<<<NPROJB * 2 + NFILLB, PT, 0, stream>>>(
        x_addr, Wp_ad, bp_ad, Wh_ad, bh_ad, att_src_at,
        x_tx, Wp_tx, bp_tx, Wh_tx, bh_tx, att_dst_at,
        z_ad, s_src, s_dst,
        e_src, e_dst, cur, csrd, ovfc, ovf);

    // grid: 8 groups x 782 blocks x 16 dst-groups = 100096 slots (li guard)
    gather_kernel<<<8 * 782, 256, 0, stream>>>(
        csrd, cur, s_src, s_dst, z_ad, batch_tx, g, cnt);

    cleanup_kernel<<<1, 256, 0, stream>>>(
        csrd, cur, ovfc, ovf, s_src, s_dst, z_ad, batch_tx, g);

    classifier_kernel<<<1, 128, 0, stream>>>(
        g, cnt, W_c1, b_c1, W_c2, b_c2, (float*)d_out);
}